// Round 1
// baseline (2515.808 us; speedup 1.0000x reference)
//
#include <hip/hip_runtime.h>
#include <math.h>

#define BATCH 16384
#define LATD 256
#define OUTD 12
#define NE 16

__device__ __forceinline__ float elu_f(float x) { return x > 0.f ? x : expm1f(x); }

// ---------------- proprio encoder: 256 ->128 elu ->64 + LN -> lat[:, 0:64] ----------------
__global__ __launch_bounds__(256) void k_proprio(
    const float* __restrict__ P,
    const float* __restrict__ W1, const float* __restrict__ B1,
    const float* __restrict__ W2, const float* __restrict__ B2,
    const float* __restrict__ G, const float* __restrict__ Bn,
    float* __restrict__ lat) {
  __shared__ __align__(16) float a[32][256];
  __shared__ float h[32][128];
  __shared__ float d[32][64];
  __shared__ float mrow[32], irow[32];
  const int t = threadIdx.x;
  const size_t row0 = (size_t)blockIdx.x * 32;
  {
    const float4* s = (const float4*)(P + row0 * 256);
    float4* dd = (float4*)&a[0][0];
    #pragma unroll
    for (int i = 0; i < 8; i++) dd[t + i * 256] = s[t + i * 256];
  }
  __syncthreads();
  {  // stage 1: [32,256] @ [256,128]
    const int c = t & 127, g0 = (t >> 7) * 16;
    float acc[16];
    #pragma unroll
    for (int i = 0; i < 16; i++) acc[i] = 0.f;
    for (int k = 0; k < 256; k++) {
      const float w = W1[k * 128 + c];
      #pragma unroll
      for (int i = 0; i < 16; i++) acc[i] += a[g0 + i][k] * w;
    }
    const float bb = B1[c];
    #pragma unroll
    for (int i = 0; i < 16; i++) h[g0 + i][c] = elu_f(acc[i] + bb);
  }
  __syncthreads();
  {  // stage 2: [32,128] @ [128,64]
    const int c = t & 63, g0 = (t >> 6) * 8;
    float acc[8];
    #pragma unroll
    for (int i = 0; i < 8; i++) acc[i] = 0.f;
    for (int k = 0; k < 128; k++) {
      const float w = W2[k * 64 + c];
      #pragma unroll
      for (int i = 0; i < 8; i++) acc[i] += h[g0 + i][k] * w;
    }
    const float bb = B2[c];
    #pragma unroll
    for (int i = 0; i < 8; i++) d[g0 + i][c] = acc[i] + bb;
  }
  __syncthreads();
  if (t < 32) {  // LN stats per row (64 wide)
    float m = 0.f;
    for (int j = 0; j < 64; j++) m += d[t][j];
    m *= (1.f / 64.f);
    float v = 0.f;
    for (int j = 0; j < 64; j++) { float x = d[t][j] - m; v += x * x; }
    v *= (1.f / 64.f);
    mrow[t] = m; irow[t] = 1.f / sqrtf(v + 1e-5f);
  }
  __syncthreads();
  for (int i = t; i < 2048; i += 256) {
    const int r = i >> 6, c = i & 63;
    lat[(row0 + r) * 256 + c] = (d[r][c] - mrow[r]) * irow[r] * G[c] + Bn[c];
  }
}

// ---------------- conv1 (1->16 s2 SAME) + conv2 (16->32 s2 SAME), elu, flatten ----------------
// SAME for in=32,k=3,s=2 -> out16, pad_lo=0 pad_hi=1; same for 16->8.
__global__ __launch_bounds__(256) void k_conv(
    const float* __restrict__ cam,
    const float* __restrict__ C1W, const float* __restrict__ C1B,
    const float* __restrict__ C2W, const float* __restrict__ C2B,
    float* __restrict__ flat) {
  __shared__ float img[32 * 33];     // pitch 33 (bank-conflict pad)
  __shared__ float w1[144];
  __shared__ float w2[4608];
  __shared__ float c1[16 * 16 * 17]; // [ci][y][x] pitch 17
  __shared__ __align__(16) float c2[2048];
  const int t = threadIdx.x;
  const size_t b = blockIdx.x;
  {
    const float* ip = cam + b * 1024;
    for (int i = t; i < 1024; i += 256) img[(i >> 5) * 33 + (i & 31)] = ip[i];
    if (t < 144) w1[t] = C1W[t];
    for (int i = t; i < 4608; i += 256) w2[i] = C2W[i];
  }
  __syncthreads();
  {  // conv1: thread = (out-ch c, out-row y), computes 16 x positions
    const int c = t >> 4, y = t & 15;
    float acc[16];
    #pragma unroll
    for (int x = 0; x < 16; x++) acc[x] = 0.f;
    #pragma unroll
    for (int dy = 0; dy < 3; dy++) {
      const int row = 2 * y + dy;
      if (row < 32) {
        float r[33];
        #pragma unroll
        for (int i = 0; i < 32; i++) r[i] = img[row * 33 + i];
        r[32] = 0.f;  // right pad
        const float wa = w1[c * 9 + dy * 3], wb = w1[c * 9 + dy * 3 + 1], wc = w1[c * 9 + dy * 3 + 2];
        #pragma unroll
        for (int x = 0; x < 16; x++) acc[x] += wa * r[2 * x] + wb * r[2 * x + 1] + wc * r[2 * x + 2];
      }
    }
    const float bb = C1B[c];
    #pragma unroll
    for (int x = 0; x < 16; x++) c1[c * 272 + y * 17 + x] = elu_f(acc[x] + bb);
  }
  __syncthreads();
  {  // conv2: thread = (out-ch co, out-row y), computes 8 x positions
    const int co = t >> 3, y = t & 7;
    float acc[8];
    #pragma unroll
    for (int x = 0; x < 8; x++) acc[x] = 0.f;
    for (int ci = 0; ci < 16; ci++) {
      float w[9];
      #pragma unroll
      for (int j = 0; j < 9; j++) w[j] = w2[(co * 16 + ci) * 9 + j];
      #pragma unroll
      for (int dy = 0; dy < 3; dy++) {
        const int row = 2 * y + dy;
        if (row < 16) {
          float r[17];
          #pragma unroll
          for (int i = 0; i < 16; i++) r[i] = c1[ci * 272 + row * 17 + i];
          r[16] = 0.f;
          #pragma unroll
          for (int x = 0; x < 8; x++)
            acc[x] += w[dy * 3] * r[2 * x] + w[dy * 3 + 1] * r[2 * x + 1] + w[dy * 3 + 2] * r[2 * x + 2];
        }
      }
    }
    const float bb = C2B[co];
    #pragma unroll
    for (int x = 0; x < 8; x++) c2[co * 64 + y * 8 + x] = elu_f(acc[x] + bb);
  }
  __syncthreads();
  {
    float4* o = (float4*)(flat + b * 2048);
    const float4* s = (const float4*)c2;
    o[t] = s[t];
    o[t + 256] = s[t + 256];
  }
}

// ---------------- cnn linear [rows,2048]@[2048,192] + bias + LN -> lat[:, 64:256] ----------------
__global__ __launch_bounds__(384) void k_cnnlin(
    const float* __restrict__ cf, const float* __restrict__ W,
    const float* __restrict__ bias, const float* __restrict__ G,
    const float* __restrict__ Bn, float* __restrict__ lat, int row_base) {
  __shared__ __align__(16) float at[32][64];
  __shared__ __align__(16) float wt[64 * 192];  // reused as y[32][192] after GEMM
  __shared__ float mrow[32], irow[32];
  const int t = threadIdx.x;
  const int b0 = blockIdx.x * 32;  // local row in chunk
  const int colg = t % 48, rowg = t / 48;  // rowg 0..7
  const int c0 = colg * 4, r0 = rowg * 4;
  float4 acc[4];
  #pragma unroll
  for (int i = 0; i < 4; i++) acc[i] = make_float4(0.f, 0.f, 0.f, 0.f);
  for (int kt = 0; kt < 32; kt++) {
    __syncthreads();
    for (int i = t; i < 512; i += 384) {
      const int r = i >> 4, kq = i & 15;
      *(float4*)&at[r][kq * 4] = *(const float4*)&cf[(size_t)(b0 + r) * 2048 + kt * 64 + kq * 4];
    }
    for (int i = t; i < 3072; i += 384) {
      const int k = i / 48, cq = i % 48;
      *(float4*)&wt[k * 192 + cq * 4] = *(const float4*)&W[(size_t)(kt * 64 + k) * 192 + cq * 4];
    }
    __syncthreads();
    for (int k = 0; k < 64; k++) {
      const float4 wv = *(const float4*)&wt[k * 192 + c0];
      #pragma unroll
      for (int i = 0; i < 4; i++) {
        const float av = at[r0 + i][k];
        acc[i].x += av * wv.x; acc[i].y += av * wv.y;
        acc[i].z += av * wv.z; acc[i].w += av * wv.w;
      }
    }
  }
  __syncthreads();
  {
    const float4 bb = *(const float4*)&bias[c0];
    #pragma unroll
    for (int i = 0; i < 4; i++) {
      float4 v;
      v.x = acc[i].x + bb.x; v.y = acc[i].y + bb.y;
      v.z = acc[i].z + bb.z; v.w = acc[i].w + bb.w;
      *(float4*)&wt[(r0 + i) * 192 + c0] = v;
    }
  }
  __syncthreads();
  if (t < 32) {
    float m = 0.f;
    for (int j = 0; j < 192; j++) m += wt[t * 192 + j];
    m *= (1.f / 192.f);
    float v = 0.f;
    for (int j = 0; j < 192; j++) { float x = wt[t * 192 + j] - m; v += x * x; }
    v *= (1.f / 192.f);
    mrow[t] = m; irow[t] = 1.f / sqrtf(v + 1e-5f);
  }
  __syncthreads();
  for (int i = t; i < 1536; i += 384) {
    const int r = i / 48, cq = i % 48;
    const float4 v = *(const float4*)&wt[r * 192 + cq * 4];
    const float4 gg = *(const float4*)&G[cq * 4];
    const float4 bb = *(const float4*)&Bn[cq * 4];
    const float m = mrow[r], iv = irow[r];
    float4 o;
    o.x = (v.x - m) * iv * gg.x + bb.x;
    o.y = (v.y - m) * iv * gg.y + bb.y;
    o.z = (v.z - m) * iv * gg.z + bb.z;
    o.w = (v.w - m) * iv * gg.w + bb.w;
    *(float4*)&lat[(size_t)(row_base + b0 + r) * 256 + 64 + cq * 4] = o;
  }
}

// ---------------- router: 256->128 elu ->64 elu ->16 softmax -> gate ----------------
__global__ __launch_bounds__(256) void k_router(
    const float* __restrict__ lat,
    const float* __restrict__ W1, const float* __restrict__ B1,
    const float* __restrict__ W2, const float* __restrict__ B2,
    const float* __restrict__ W3, const float* __restrict__ B3,
    float* __restrict__ gate) {
  __shared__ __align__(16) float a[32][256];
  __shared__ float h1[32][128];
  __shared__ float h2[32][64];
  __shared__ float lg[32][16];
  const int t = threadIdx.x;
  const size_t row0 = (size_t)blockIdx.x * 32;
  {
    const float4* s = (const float4*)(lat + row0 * 256);
    float4* dd = (float4*)&a[0][0];
    #pragma unroll
    for (int i = 0; i < 8; i++) dd[t + i * 256] = s[t + i * 256];
  }
  __syncthreads();
  {
    const int c = t & 127, g0 = (t >> 7) * 16;
    float acc[16];
    #pragma unroll
    for (int i = 0; i < 16; i++) acc[i] = 0.f;
    for (int k = 0; k < 256; k++) {
      const float w = W1[k * 128 + c];
      #pragma unroll
      for (int i = 0; i < 16; i++) acc[i] += a[g0 + i][k] * w;
    }
    const float bb = B1[c];
    #pragma unroll
    for (int i = 0; i < 16; i++) h1[g0 + i][c] = elu_f(acc[i] + bb);
  }
  __syncthreads();
  {
    const int c = t & 63, g0 = (t >> 6) * 8;
    float acc[8];
    #pragma unroll
    for (int i = 0; i < 8; i++) acc[i] = 0.f;
    for (int k = 0; k < 128; k++) {
      const float w = W2[k * 64 + c];
      #pragma unroll
      for (int i = 0; i < 8; i++) acc[i] += h1[g0 + i][k] * w;
    }
    const float bb = B2[c];
    #pragma unroll
    for (int i = 0; i < 8; i++) h2[g0 + i][c] = elu_f(acc[i] + bb);
  }
  __syncthreads();
  for (int o = t; o < 512; o += 256) {
    const int r = o >> 4, c = o & 15;
    float acc = 0.f;
    for (int k = 0; k < 64; k++) acc += h2[r][k] * W3[k * 16 + c];
    lg[r][c] = acc + B3[c];
  }
  __syncthreads();
  if (t < 32) {
    float m = lg[t][0];
    for (int c = 1; c < 16; c++) m = fmaxf(m, lg[t][c]);
    float s = 0.f;
    float ex[16];
    for (int c = 0; c < 16; c++) { ex[c] = expf(lg[t][c] - m); s += ex[c]; }
    const float inv = 1.f / s;
    for (int c = 0; c < 16; c++) gate[(row0 + t) * 16 + c] = ex[c] * inv;
  }
}

// ---------------- experts: 3x(256->256 elu) + 256->12, gate-weighted atomic combine ----------------
__global__ __launch_bounds__(256) void k_experts(
    const float* __restrict__ lat, const float* __restrict__ gate,
    const float* __restrict__ EW1, const float* __restrict__ EB1,
    const float* __restrict__ EW2, const float* __restrict__ EB2,
    const float* __restrict__ EW3, const float* __restrict__ EB3,
    const float* __restrict__ EW4, const float* __restrict__ EB4,
    float* __restrict__ out) {
  __shared__ __align__(16) float xa[32][256];
  __shared__ __align__(16) float xb[32][256];
  const int t = threadIdx.x;
  const int e = blockIdx.y;
  const size_t row0 = (size_t)blockIdx.x * 32;
  {
    const float4* s = (const float4*)(lat + row0 * 256);
    float4* dd = (float4*)&xa[0][0];
    #pragma unroll
    for (int i = 0; i < 8; i++) dd[t + i * 256] = s[t + i * 256];
  }
  __syncthreads();
  const int c0 = (t & 63) * 4, rg = (t >> 6) * 8;
  float (*src)[256] = xa;
  float (*dst)[256] = xb;
  const float* Wl[3] = { EW1 + (size_t)e * 65536, EW2 + (size_t)e * 65536, EW3 + (size_t)e * 65536 };
  const float* Bl[3] = { EB1 + e * 256, EB2 + e * 256, EB3 + e * 256 };
  #pragma unroll
  for (int l = 0; l < 3; l++) {
    const float* W = Wl[l];
    float4 acc[8];
    #pragma unroll
    for (int i = 0; i < 8; i++) acc[i] = make_float4(0.f, 0.f, 0.f, 0.f);
    for (int k = 0; k < 256; k += 4) {
      const float4 w0 = *(const float4*)(W + (size_t)(k + 0) * 256 + c0);
      const float4 w1 = *(const float4*)(W + (size_t)(k + 1) * 256 + c0);
      const float4 w2 = *(const float4*)(W + (size_t)(k + 2) * 256 + c0);
      const float4 w3 = *(const float4*)(W + (size_t)(k + 3) * 256 + c0);
      #pragma unroll
      for (int i = 0; i < 8; i++) {
        const float4 av = *(const float4*)&src[rg + i][k];
        acc[i].x += av.x * w0.x + av.y * w1.x + av.z * w2.x + av.w * w3.x;
        acc[i].y += av.x * w0.y + av.y * w1.y + av.z * w2.y + av.w * w3.y;
        acc[i].z += av.x * w0.z + av.y * w1.z + av.z * w2.z + av.w * w3.z;
        acc[i].w += av.x * w0.w + av.y * w1.w + av.z * w2.w + av.w * w3.w;
      }
    }
    const float4 bb = *(const float4*)(Bl[l] + c0);
    #pragma unroll
    for (int i = 0; i < 8; i++) {
      float4 v;
      v.x = elu_f(acc[i].x + bb.x);
      v.y = elu_f(acc[i].y + bb.y);
      v.z = elu_f(acc[i].z + bb.z);
      v.w = elu_f(acc[i].w + bb.w);
      *(float4*)&dst[rg + i][c0] = v;
    }
    __syncthreads();
    float (*tmp)[256] = src; src = dst; dst = tmp;
  }
  // layer 4 (256 -> 12) + gated combine
  const float* W4 = EW4 + (size_t)e * 3072;
  const float* B4 = EB4 + e * 12;
  for (int o = t; o < 384; o += 256) {
    const int r = o / 12, c = o % 12;
    float acc = 0.f;
    for (int k = 0; k < 256; k++) acc += src[r][k] * W4[k * 12 + c];
    const float gv = gate[(row0 + r) * 16 + e];
    atomicAdd(&out[(row0 + r) * 12 + c], gv * (acc + B4[c]));
  }
}

extern "C" void kernel_launch(void* const* d_in, const int* in_sizes, int n_in,
                              void* d_out, int out_size, void* d_ws, size_t ws_size,
                              hipStream_t stream) {
  (void)in_sizes; (void)n_in; (void)out_size; (void)ws_size;
  const float* proprio   = (const float*)d_in[0];
  const float* camera    = (const float*)d_in[1];
  const float* enc_w1    = (const float*)d_in[2];
  const float* enc_b1    = (const float*)d_in[3];
  const float* enc_w2    = (const float*)d_in[4];
  const float* enc_b2    = (const float*)d_in[5];
  const float* enc_ln_g  = (const float*)d_in[6];
  const float* enc_ln_b  = (const float*)d_in[7];
  const float* conv1_w   = (const float*)d_in[8];
  const float* conv1_b   = (const float*)d_in[9];
  const float* conv2_w   = (const float*)d_in[10];
  const float* conv2_b   = (const float*)d_in[11];
  const float* cnn_lin_w = (const float*)d_in[12];
  const float* cnn_lin_b = (const float*)d_in[13];
  const float* cnn_ln_g  = (const float*)d_in[14];
  const float* cnn_ln_b  = (const float*)d_in[15];
  const float* rw1 = (const float*)d_in[16];
  const float* rb1 = (const float*)d_in[17];
  const float* rw2 = (const float*)d_in[18];
  const float* rb2 = (const float*)d_in[19];
  const float* rw3 = (const float*)d_in[20];
  const float* rb3 = (const float*)d_in[21];
  const float* ew1 = (const float*)d_in[22];
  const float* eb1 = (const float*)d_in[23];
  const float* ew2 = (const float*)d_in[24];
  const float* eb2 = (const float*)d_in[25];
  const float* ew3 = (const float*)d_in[26];
  const float* eb3 = (const float*)d_in[27];
  const float* ew4 = (const float*)d_in[28];
  const float* eb4 = (const float*)d_in[29];
  float* out = (float*)d_out;

  // ws layout: lat[B,256] | gate[B,16] | convflat[8192,2048]  (~81 MB)
  float* lat      = (float*)d_ws;
  float* gate     = lat + (size_t)BATCH * LATD;
  float* convflat = gate + (size_t)BATCH * NE;

  hipMemsetAsync(d_out, 0, (size_t)BATCH * OUTD * sizeof(float), stream);
  k_proprio<<<dim3(512), dim3(256), 0, stream>>>(proprio, enc_w1, enc_b1, enc_w2, enc_b2,
                                                 enc_ln_g, enc_ln_b, lat);
  for (int ch = 0; ch < 2; ch++) {
    k_conv<<<dim3(8192), dim3(256), 0, stream>>>(camera + (size_t)ch * 8192 * 1024,
                                                 conv1_w, conv1_b, conv2_w, conv2_b, convflat);
    k_cnnlin<<<dim3(256), dim3(384), 0, stream>>>(convflat, cnn_lin_w, cnn_lin_b,
                                                  cnn_ln_g, cnn_ln_b, lat, ch * 8192);
  }
  k_router<<<dim3(512), dim3(256), 0, stream>>>(lat, rw1, rb1, rw2, rb2, rw3, rb3, gate);
  k_experts<<<dim3(512, 16), dim3(256), 0, stream>>>(lat, gate, ew1, eb1, ew2, eb2,
                                                     ew3, eb3, ew4, eb4, out);
}

// Round 2
// 1480.393 us; speedup vs baseline: 1.6994x; 1.6994x over previous
//
#include <hip/hip_runtime.h>
#include <math.h>

#define BATCH 16384
#define LATD 256
#define OUTD 12
#define NE 16

typedef short bf16x8 __attribute__((ext_vector_type(8)));
typedef float f32x4 __attribute__((ext_vector_type(4)));

__device__ __forceinline__ float elu_f(float x) { return x > 0.f ? x : expm1f(x); }
__device__ __forceinline__ float elu_fast(float x) { return x > 0.f ? x : (__expf(x) - 1.f); }

__device__ __forceinline__ unsigned short f2bf(float f) {
  union { float f; unsigned int u; } a; a.f = f;
  unsigned int u = a.u;
  unsigned int r = (u + 0x7FFFu + ((u >> 16) & 1u)) >> 16;
  return (unsigned short)r;
}

// XOR swizzle on LDS byte address: spreads stride-512B rows across banks.
__device__ __forceinline__ int swz(int b) { return b ^ (((b >> 9) & 7) << 4); }

// ---------------- proprio encoder: 256 ->128 elu ->64 + LN -> lat[:, 0:64] ----------------
__global__ __launch_bounds__(256) void k_proprio(
    const float* __restrict__ P,
    const float* __restrict__ W1, const float* __restrict__ B1,
    const float* __restrict__ W2, const float* __restrict__ B2,
    const float* __restrict__ G, const float* __restrict__ Bn,
    float* __restrict__ lat) {
  __shared__ __align__(16) float a[32][256];
  __shared__ float h[32][128];
  __shared__ float d[32][64];
  __shared__ float mrow[32], irow[32];
  const int t = threadIdx.x;
  const size_t row0 = (size_t)blockIdx.x * 32;
  {
    const float4* s = (const float4*)(P + row0 * 256);
    float4* dd = (float4*)&a[0][0];
    #pragma unroll
    for (int i = 0; i < 8; i++) dd[t + i * 256] = s[t + i * 256];
  }
  __syncthreads();
  {
    const int c = t & 127, g0 = (t >> 7) * 16;
    float acc[16];
    #pragma unroll
    for (int i = 0; i < 16; i++) acc[i] = 0.f;
    for (int k = 0; k < 256; k++) {
      const float w = W1[k * 128 + c];
      #pragma unroll
      for (int i = 0; i < 16; i++) acc[i] += a[g0 + i][k] * w;
    }
    const float bb = B1[c];
    #pragma unroll
    for (int i = 0; i < 16; i++) h[g0 + i][c] = elu_f(acc[i] + bb);
  }
  __syncthreads();
  {
    const int c = t & 63, g0 = (t >> 6) * 8;
    float acc[8];
    #pragma unroll
    for (int i = 0; i < 8; i++) acc[i] = 0.f;
    for (int k = 0; k < 128; k++) {
      const float w = W2[k * 64 + c];
      #pragma unroll
      for (int i = 0; i < 8; i++) acc[i] += h[g0 + i][k] * w;
    }
    const float bb = B2[c];
    #pragma unroll
    for (int i = 0; i < 8; i++) d[g0 + i][c] = acc[i] + bb;
  }
  __syncthreads();
  if (t < 32) {
    float m = 0.f;
    for (int j = 0; j < 64; j++) m += d[t][j];
    m *= (1.f / 64.f);
    float v = 0.f;
    for (int j = 0; j < 64; j++) { float x = d[t][j] - m; v += x * x; }
    v *= (1.f / 64.f);
    mrow[t] = m; irow[t] = 1.f / sqrtf(v + 1e-5f);
  }
  __syncthreads();
  for (int i = t; i < 2048; i += 256) {
    const int r = i >> 6, c = i & 63;
    lat[(row0 + r) * 256 + c] = (d[r][c] - mrow[r]) * irow[r] * G[c] + Bn[c];
  }
}

// ---------------- conv1 + conv2, elu, flatten ----------------
__global__ __launch_bounds__(256) void k_conv(
    const float* __restrict__ cam,
    const float* __restrict__ C1W, const float* __restrict__ C1B,
    const float* __restrict__ C2W, const float* __restrict__ C2B,
    float* __restrict__ flat) {
  __shared__ float img[32 * 33];
  __shared__ float w1[144];
  __shared__ float w2[4608];
  __shared__ float c1[16 * 16 * 17];
  __shared__ __align__(16) float c2[2048];
  const int t = threadIdx.x;
  const size_t b = blockIdx.x;
  {
    const float* ip = cam + b * 1024;
    for (int i = t; i < 1024; i += 256) img[(i >> 5) * 33 + (i & 31)] = ip[i];
    if (t < 144) w1[t] = C1W[t];
    for (int i = t; i < 4608; i += 256) w2[i] = C2W[i];
  }
  __syncthreads();
  {
    const int c = t >> 4, y = t & 15;
    float acc[16];
    #pragma unroll
    for (int x = 0; x < 16; x++) acc[x] = 0.f;
    #pragma unroll
    for (int dy = 0; dy < 3; dy++) {
      const int row = 2 * y + dy;
      if (row < 32) {
        float r[33];
        #pragma unroll
        for (int i = 0; i < 32; i++) r[i] = img[row * 33 + i];
        r[32] = 0.f;
        const float wa = w1[c * 9 + dy * 3], wb = w1[c * 9 + dy * 3 + 1], wc = w1[c * 9 + dy * 3 + 2];
        #pragma unroll
        for (int x = 0; x < 16; x++) acc[x] += wa * r[2 * x] + wb * r[2 * x + 1] + wc * r[2 * x + 2];
      }
    }
    const float bb = C1B[c];
    #pragma unroll
    for (int x = 0; x < 16; x++) c1[c * 272 + y * 17 + x] = elu_f(acc[x] + bb);
  }
  __syncthreads();
  {
    const int co = t >> 3, y = t & 7;
    float acc[8];
    #pragma unroll
    for (int x = 0; x < 8; x++) acc[x] = 0.f;
    for (int ci = 0; ci < 16; ci++) {
      float w[9];
      #pragma unroll
      for (int j = 0; j < 9; j++) w[j] = w2[(co * 16 + ci) * 9 + j];
      #pragma unroll
      for (int dy = 0; dy < 3; dy++) {
        const int row = 2 * y + dy;
        if (row < 16) {
          float r[17];
          #pragma unroll
          for (int i = 0; i < 16; i++) r[i] = c1[ci * 272 + row * 17 + i];
          r[16] = 0.f;
          #pragma unroll
          for (int x = 0; x < 8; x++)
            acc[x] += w[dy * 3] * r[2 * x] + w[dy * 3 + 1] * r[2 * x + 1] + w[dy * 3 + 2] * r[2 * x + 2];
        }
      }
    }
    const float bb = C2B[co];
    #pragma unroll
    for (int x = 0; x < 8; x++) c2[co * 64 + y * 8 + x] = elu_f(acc[x] + bb);
  }
  __syncthreads();
  {
    float4* o = (float4*)(flat + b * 2048);
    const float4* s = (const float4*)c2;
    o[t] = s[t];
    o[t + 256] = s[t + 256];
  }
}

// ---------------- cnn linear + bias + LN -> lat[:, 64:256] ----------------
__global__ __launch_bounds__(384) void k_cnnlin(
    const float* __restrict__ cf, const float* __restrict__ W,
    const float* __restrict__ bias, const float* __restrict__ G,
    const float* __restrict__ Bn, float* __restrict__ lat, int row_base) {
  __shared__ __align__(16) float at[32][64];
  __shared__ __align__(16) float wt[64 * 192];
  __shared__ float mrow[32], irow[32];
  const int t = threadIdx.x;
  const int b0 = blockIdx.x * 32;
  const int colg = t % 48, rowg = t / 48;
  const int c0 = colg * 4, r0 = rowg * 4;
  float4 acc[4];
  #pragma unroll
  for (int i = 0; i < 4; i++) acc[i] = make_float4(0.f, 0.f, 0.f, 0.f);
  for (int kt = 0; kt < 32; kt++) {
    __syncthreads();
    for (int i = t; i < 512; i += 384) {
      const int r = i >> 4, kq = i & 15;
      *(float4*)&at[r][kq * 4] = *(const float4*)&cf[(size_t)(b0 + r) * 2048 + kt * 64 + kq * 4];
    }
    for (int i = t; i < 3072; i += 384) {
      const int k = i / 48, cq = i % 48;
      *(float4*)&wt[k * 192 + cq * 4] = *(const float4*)&W[(size_t)(kt * 64 + k) * 192 + cq * 4];
    }
    __syncthreads();
    for (int k = 0; k < 64; k++) {
      const float4 wv = *(const float4*)&wt[k * 192 + c0];
      #pragma unroll
      for (int i = 0; i < 4; i++) {
        const float av = at[r0 + i][k];
        acc[i].x += av * wv.x; acc[i].y += av * wv.y;
        acc[i].z += av * wv.z; acc[i].w += av * wv.w;
      }
    }
  }
  __syncthreads();
  {
    const float4 bb = *(const float4*)&bias[c0];
    #pragma unroll
    for (int i = 0; i < 4; i++) {
      float4 v;
      v.x = acc[i].x + bb.x; v.y = acc[i].y + bb.y;
      v.z = acc[i].z + bb.z; v.w = acc[i].w + bb.w;
      *(float4*)&wt[(r0 + i) * 192 + c0] = v;
    }
  }
  __syncthreads();
  if (t < 32) {
    float m = 0.f;
    for (int j = 0; j < 192; j++) m += wt[t * 192 + j];
    m *= (1.f / 192.f);
    float v = 0.f;
    for (int j = 0; j < 192; j++) { float x = wt[t * 192 + j] - m; v += x * x; }
    v *= (1.f / 192.f);
    mrow[t] = m; irow[t] = 1.f / sqrtf(v + 1e-5f);
  }
  __syncthreads();
  for (int i = t; i < 1536; i += 384) {
    const int r = i / 48, cq = i % 48;
    const float4 v = *(const float4*)&wt[r * 192 + cq * 4];
    const float4 gg = *(const float4*)&G[cq * 4];
    const float4 bb = *(const float4*)&Bn[cq * 4];
    const float m = mrow[r], iv = irow[r];
    float4 o;
    o.x = (v.x - m) * iv * gg.x + bb.x;
    o.y = (v.y - m) * iv * gg.y + bb.y;
    o.z = (v.z - m) * iv * gg.z + bb.z;
    o.w = (v.w - m) * iv * gg.w + bb.w;
    *(float4*)&lat[(size_t)(row_base + b0 + r) * 256 + 64 + cq * 4] = o;
  }
}

// ---------------- router ----------------
__global__ __launch_bounds__(256) void k_router(
    const float* __restrict__ lat,
    const float* __restrict__ W1, const float* __restrict__ B1,
    const float* __restrict__ W2, const float* __restrict__ B2,
    const float* __restrict__ W3, const float* __restrict__ B3,
    float* __restrict__ gate) {
  __shared__ __align__(16) float a[32][256];
  __shared__ float h1[32][128];
  __shared__ float h2[32][64];
  __shared__ float lg[32][16];
  const int t = threadIdx.x;
  const size_t row0 = (size_t)blockIdx.x * 32;
  {
    const float4* s = (const float4*)(lat + row0 * 256);
    float4* dd = (float4*)&a[0][0];
    #pragma unroll
    for (int i = 0; i < 8; i++) dd[t + i * 256] = s[t + i * 256];
  }
  __syncthreads();
  {
    const int c = t & 127, g0 = (t >> 7) * 16;
    float acc[16];
    #pragma unroll
    for (int i = 0; i < 16; i++) acc[i] = 0.f;
    for (int k = 0; k < 256; k++) {
      const float w = W1[k * 128 + c];
      #pragma unroll
      for (int i = 0; i < 16; i++) acc[i] += a[g0 + i][k] * w;
    }
    const float bb = B1[c];
    #pragma unroll
    for (int i = 0; i < 16; i++) h1[g0 + i][c] = elu_f(acc[i] + bb);
  }
  __syncthreads();
  {
    const int c = t & 63, g0 = (t >> 6) * 8;
    float acc[8];
    #pragma unroll
    for (int i = 0; i < 8; i++) acc[i] = 0.f;
    for (int k = 0; k < 128; k++) {
      const float w = W2[k * 64 + c];
      #pragma unroll
      for (int i = 0; i < 8; i++) acc[i] += h1[g0 + i][k] * w;
    }
    const float bb = B2[c];
    #pragma unroll
    for (int i = 0; i < 8; i++) h2[g0 + i][c] = elu_f(acc[i] + bb);
  }
  __syncthreads();
  for (int o = t; o < 512; o += 256) {
    const int r = o >> 4, c = o & 15;
    float acc = 0.f;
    for (int k = 0; k < 64; k++) acc += h2[r][k] * W3[k * 16 + c];
    lg[r][c] = acc + B3[c];
  }
  __syncthreads();
  if (t < 32) {
    float m = lg[t][0];
    for (int c = 1; c < 16; c++) m = fmaxf(m, lg[t][c]);
    float s = 0.f;
    float ex[16];
    for (int c = 0; c < 16; c++) { ex[c] = expf(lg[t][c] - m); s += ex[c]; }
    const float inv = 1.f / s;
    for (int c = 0; c < 16; c++) gate[(row0 + t) * 16 + c] = ex[c] * inv;
  }
}

// ---------------- weight transpose+convert: ew[e][k][j] f32 -> Wt[e][j][k] bf16 ----------------
__global__ __launch_bounds__(256) void k_wt(
    const float* __restrict__ ew1, const float* __restrict__ ew2, const float* __restrict__ ew3,
    unsigned short* __restrict__ wt1, unsigned short* __restrict__ wt2, unsigned short* __restrict__ wt3) {
  __shared__ float tile[64][65];
  const int t = threadIdx.x;
  const int zl = blockIdx.z;
  const int layer = zl >> 4, e = zl & 15;
  const float* src = (layer == 0 ? ew1 : layer == 1 ? ew2 : ew3) + (size_t)e * 65536;
  unsigned short* dst = (layer == 0 ? wt1 : layer == 1 ? wt2 : wt3) + (size_t)e * 65536;
  const int k0 = blockIdx.x * 64, j0 = blockIdx.y * 64;
  for (int idx = t; idx < 4096; idx += 256) {
    const int kk = idx >> 6, jj = idx & 63;
    tile[kk][jj] = src[(size_t)(k0 + kk) * 256 + j0 + jj];
  }
  __syncthreads();
  for (int idx = t; idx < 4096; idx += 256) {
    const int jj = idx >> 6, kk = idx & 63;
    dst[(size_t)(j0 + jj) * 256 + k0 + kk] = f2bf(tile[kk][jj]);
  }
}

// ---------------- ew4[e][k][12] f32 -> W4t[e][16][256] bf16 (padded) ----------------
__global__ __launch_bounds__(256) void k_w4t(
    const float* __restrict__ ew4, unsigned short* __restrict__ w4t) {
  const int e = blockIdx.x, k = threadIdx.x;
  #pragma unroll
  for (int j = 0; j < 16; j++) {
    const float v = (j < 12) ? ew4[(size_t)e * 3072 + k * 12 + j] : 0.f;
    w4t[(size_t)e * 4096 + j * 256 + k] = f2bf(v);
  }
}

// ---------------- experts: bf16 MFMA fused 4-layer MLP ----------------
// block: 64 rows x 1 expert, 4 waves. X in LDS [64][256] bf16, XOR-swizzled.
// Yt = Wt . Xt via mfma_16x16x32_bf16: A=weight (j=lane%16, k contiguous),
// B=X (m=lane%16, k contiguous), D: col=lane%16 -> m, row=4*(lane>>4)+reg -> j.
__global__ __launch_bounds__(256) void k_experts(
    const float* __restrict__ lat, const float* __restrict__ gate,
    const unsigned short* __restrict__ wt1, const unsigned short* __restrict__ wt2,
    const unsigned short* __restrict__ wt3, const unsigned short* __restrict__ w4t,
    const float* __restrict__ EB1, const float* __restrict__ EB2,
    const float* __restrict__ EB3, const float* __restrict__ EB4,
    float* __restrict__ eout) {
  __shared__ __align__(16) unsigned short X[64 * 256];
  char* xb = (char*)X;
  const int t = threadIdx.x;
  const int lane = t & 63, w = t >> 6;
  const int lr = lane & 15, lg = lane >> 4;
  const int e = blockIdx.y;
  const int row0 = blockIdx.x * 64;

  // stage latent (f32 -> bf16, swizzled)
  #pragma unroll
  for (int i = 0; i < 16; i++) {
    const int f = t + i * 256;            // float4 index over 64x256
    const int m = f >> 6;
    const int k0 = (f & 63) * 4;
    const float4 v = *(const float4*)(lat + (size_t)(row0 + m) * 256 + k0);
    ushort4 h;
    h.x = f2bf(v.x); h.y = f2bf(v.y); h.z = f2bf(v.z); h.w = f2bf(v.w);
    *(ushort4*)(xb + swz(m * 512 + k0 * 2)) = h;
  }
  __syncthreads();

  const unsigned short* Wl[3] = {
    wt1 + (size_t)e * 65536, wt2 + (size_t)e * 65536, wt3 + (size_t)e * 65536 };
  const float* Bl[3] = { EB1 + e * 256, EB2 + e * 256, EB3 + e * 256 };
  const int wjb = w * 64;

  int mtb[4];
  #pragma unroll
  for (int mt = 0; mt < 4; mt++) mtb[mt] = (mt * 16 + lr) * 512 + lg * 16;

  #pragma unroll
  for (int l = 0; l < 3; l++) {
    const unsigned short* W = Wl[l];
    f32x4 acc[4][4];
    #pragma unroll
    for (int jt = 0; jt < 4; jt++)
      #pragma unroll
      for (int mt = 0; mt < 4; mt++) acc[jt][mt] = (f32x4){0.f, 0.f, 0.f, 0.f};
    const size_t wlane = (size_t)(wjb + lr) * 256 + lg * 8;
    for (int ks = 0; ks < 8; ks++) {
      bf16x8 af[4], bfr[4];
      #pragma unroll
      for (int jt = 0; jt < 4; jt++)
        af[jt] = *(const bf16x8*)(W + wlane + jt * 4096 + ks * 32);
      #pragma unroll
      for (int mt = 0; mt < 4; mt++)
        bfr[mt] = *(const bf16x8*)(xb + swz(mtb[mt] + ks * 64));
      #pragma unroll
      for (int jt = 0; jt < 4; jt++)
        #pragma unroll
        for (int mt = 0; mt < 4; mt++)
          acc[jt][mt] = __builtin_amdgcn_mfma_f32_16x16x32_bf16(af[jt], bfr[mt], acc[jt][mt], 0, 0, 0);
    }
    __syncthreads();  // everyone done reading X
    const float* B = Bl[l];
    #pragma unroll
    for (int jt = 0; jt < 4; jt++) {
      const int j0 = wjb + jt * 16 + 4 * lg;
      const float4 bb = *(const float4*)(B + j0);
      #pragma unroll
      for (int mt = 0; mt < 4; mt++) {
        const int m = mt * 16 + lr;
        ushort4 h;
        h.x = f2bf(elu_fast(acc[jt][mt].x + bb.x));
        h.y = f2bf(elu_fast(acc[jt][mt].y + bb.y));
        h.z = f2bf(elu_fast(acc[jt][mt].z + bb.z));
        h.w = f2bf(elu_fast(acc[jt][mt].w + bb.w));
        *(ushort4*)(xb + swz(m * 512 + j0 * 2)) = h;
      }
    }
    __syncthreads();  // next-layer X ready
  }

  // layer 4: [16(pad) x 256] . Xt -> per-wave row-tile mt = w
  {
    const unsigned short* W4 = w4t + (size_t)e * 4096;
    f32x4 a4 = (f32x4){0.f, 0.f, 0.f, 0.f};
    const size_t wl4 = (size_t)lr * 256 + lg * 8;
    const int mb = (w * 16 + lr) * 512 + lg * 16;
    for (int ks = 0; ks < 8; ks++) {
      const bf16x8 a = *(const bf16x8*)(W4 + wl4 + ks * 32);
      const bf16x8 b = *(const bf16x8*)(xb + swz(mb + ks * 64));
      a4 = __builtin_amdgcn_mfma_f32_16x16x32_bf16(a, b, a4, 0, 0, 0);
    }
    const int row = row0 + w * 16 + lr;
    const float gv = gate[(size_t)row * 16 + e];
    if (lg < 3) {
      const float4 bb = *(const float4*)(EB4 + e * 12 + 4 * lg);
      float4 o;
      o.x = gv * (a4.x + bb.x);
      o.y = gv * (a4.y + bb.y);
      o.z = gv * (a4.z + bb.z);
      o.w = gv * (a4.w + bb.w);
      *(float4*)(eout + ((size_t)e * BATCH + row) * 12 + 4 * lg) = o;
    }
  }
}

// ---------------- sum over experts ----------------
__global__ __launch_bounds__(256) void k_reduce(
    const float* __restrict__ eout, float* __restrict__ out) {
  const int i = blockIdx.x * 256 + threadIdx.x;
  if (i < BATCH * OUTD) {
    float s = 0.f;
    #pragma unroll
    for (int e = 0; e < NE; e++) s += eout[(size_t)e * (BATCH * OUTD) + i];
    out[i] = s;
  }
}

extern "C" void kernel_launch(void* const* d_in, const int* in_sizes, int n_in,
                              void* d_out, int out_size, void* d_ws, size_t ws_size,
                              hipStream_t stream) {
  (void)in_sizes; (void)n_in; (void)out_size; (void)ws_size;
  const float* proprio   = (const float*)d_in[0];
  const float* camera    = (const float*)d_in[1];
  const float* enc_w1    = (const float*)d_in[2];
  const float* enc_b1    = (const float*)d_in[3];
  const float* enc_w2    = (const float*)d_in[4];
  const float* enc_b2    = (const float*)d_in[5];
  const float* enc_ln_g  = (const float*)d_in[6];
  const float* enc_ln_b  = (const float*)d_in[7];
  const float* conv1_w   = (const float*)d_in[8];
  const float* conv1_b   = (const float*)d_in[9];
  const float* conv2_w   = (const float*)d_in[10];
  const float* conv2_b   = (const float*)d_in[11];
  const float* cnn_lin_w = (const float*)d_in[12];
  const float* cnn_lin_b = (const float*)d_in[13];
  const float* cnn_ln_g  = (const float*)d_in[14];
  const float* cnn_ln_b  = (const float*)d_in[15];
  const float* rw1 = (const float*)d_in[16];
  const float* rb1 = (const float*)d_in[17];
  const float* rw2 = (const float*)d_in[18];
  const float* rb2 = (const float*)d_in[19];
  const float* rw3 = (const float*)d_in[20];
  const float* rb3 = (const float*)d_in[21];
  const float* ew1 = (const float*)d_in[22];
  const float* eb1 = (const float*)d_in[23];
  const float* ew2 = (const float*)d_in[24];
  const float* eb2 = (const float*)d_in[25];
  const float* ew3 = (const float*)d_in[26];
  const float* eb3 = (const float*)d_in[27];
  const float* ew4 = (const float*)d_in[28];
  const float* eb4 = (const float*)d_in[29];
  float* out = (float*)d_out;

  // ws layout (all 16B-aligned):
  // lat[B,256] f32 | gate[B,16] f32 | eout[16,B,12] f32 |
  // wt1,wt2,wt3[16,256,256] bf16 | w4t[16,16,256] bf16 | convflat[4096,2048] f32
  float* lat  = (float*)d_ws;
  float* gate = lat + (size_t)BATCH * LATD;                 // 4,194,304
  float* eout = gate + (size_t)BATCH * NE;                  // +262,144
  unsigned short* wt1 = (unsigned short*)(eout + (size_t)NE * BATCH * OUTD);
  unsigned short* wt2 = wt1 + (size_t)NE * 65536;
  unsigned short* wt3 = wt2 + (size_t)NE * 65536;
  unsigned short* w4t = wt3 + (size_t)NE * 65536;
  float* convflat = (float*)(w4t + (size_t)NE * 4096);

  k_wt<<<dim3(4, 4, 48), dim3(256), 0, stream>>>(ew1, ew2, ew3, wt1, wt2, wt3);
  k_w4t<<<dim3(16), dim3(256), 0, stream>>>(ew4, w4t);
  k_proprio<<<dim3(512), dim3(256), 0, stream>>>(proprio, enc_w1, enc_b1, enc_w2, enc_b2,
                                                 enc_ln_g, enc_ln_b, lat);
  for (int ch = 0; ch < 4; ch++) {
    k_conv<<<dim3(4096), dim3(256), 0, stream>>>(camera + (size_t)ch * 4096 * 1024,
                                                 conv1_w, conv1_b, conv2_w, conv2_b, convflat);
    k_cnnlin<<<dim3(128), dim3(384), 0, stream>>>(convflat, cnn_lin_w, cnn_lin_b,
                                                  cnn_ln_g, cnn_ln_b, lat, ch * 4096);
  }
  k_router<<<dim3(512), dim3(256), 0, stream>>>(lat, rw1, rb1, rw2, rb2, rw3, rb3, gate);
  k_experts<<<dim3(256, 16), dim3(256), 0, stream>>>(lat, gate, wt1, wt2, wt3, w4t,
                                                     eb1, eb2, eb3, eb4, eout);
  k_reduce<<<dim3(768), dim3(256), 0, stream>>>(eout, out);
}

// Round 3
// 814.265 us; speedup vs baseline: 3.0897x; 1.8181x over previous
//
#include <hip/hip_runtime.h>
#include <math.h>

#define BATCH 16384
#define LATD 256
#define OUTD 12
#define NE 16

typedef short bf16x8 __attribute__((ext_vector_type(8)));
typedef float f32x4 __attribute__((ext_vector_type(4)));
typedef unsigned short u16x8 __attribute__((ext_vector_type(8)));

__device__ __forceinline__ float elu_f(float x) { return x > 0.f ? x : expm1f(x); }
__device__ __forceinline__ float elu_fast(float x) { return x > 0.f ? x : (__expf(x) - 1.f); }

__device__ __forceinline__ unsigned short f2bf(float f) {
  union { float f; unsigned int u; } a; a.f = f;
  unsigned int u = a.u;
  unsigned int r = (u + 0x7FFFu + ((u >> 16) & 1u)) >> 16;
  return (unsigned short)r;
}

// XOR swizzle on LDS byte address for 512B-row tiles (bank-conflict fix).
__device__ __forceinline__ int swz(int b) { return b ^ (((b >> 9) & 7) << 4); }

// ---------------- proprio encoder: 256 ->128 elu ->64 + LN -> lat[:, 0:64] ----------------
__global__ __launch_bounds__(256) void k_proprio(
    const float* __restrict__ P,
    const float* __restrict__ W1, const float* __restrict__ B1,
    const float* __restrict__ W2, const float* __restrict__ B2,
    const float* __restrict__ G, const float* __restrict__ Bn,
    float* __restrict__ lat) {
  __shared__ __align__(16) float a[32][256];
  __shared__ float h[32][128];
  __shared__ float d[32][64];
  __shared__ float mrow[32], irow[32];
  const int t = threadIdx.x;
  const size_t row0 = (size_t)blockIdx.x * 32;
  {
    const float4* s = (const float4*)(P + row0 * 256);
    float4* dd = (float4*)&a[0][0];
    #pragma unroll
    for (int i = 0; i < 8; i++) dd[t + i * 256] = s[t + i * 256];
  }
  __syncthreads();
  {
    const int c = t & 127, g0 = (t >> 7) * 16;
    float acc[16];
    #pragma unroll
    for (int i = 0; i < 16; i++) acc[i] = 0.f;
    for (int k = 0; k < 256; k++) {
      const float w = W1[k * 128 + c];
      #pragma unroll
      for (int i = 0; i < 16; i++) acc[i] += a[g0 + i][k] * w;
    }
    const float bb = B1[c];
    #pragma unroll
    for (int i = 0; i < 16; i++) h[g0 + i][c] = elu_f(acc[i] + bb);
  }
  __syncthreads();
  {
    const int c = t & 63, g0 = (t >> 6) * 8;
    float acc[8];
    #pragma unroll
    for (int i = 0; i < 8; i++) acc[i] = 0.f;
    for (int k = 0; k < 128; k++) {
      const float w = W2[k * 64 + c];
      #pragma unroll
      for (int i = 0; i < 8; i++) acc[i] += h[g0 + i][k] * w;
    }
    const float bb = B2[c];
    #pragma unroll
    for (int i = 0; i < 8; i++) d[g0 + i][c] = acc[i] + bb;
  }
  __syncthreads();
  if (t < 32) {
    float m = 0.f;
    for (int j = 0; j < 64; j++) m += d[t][j];
    m *= (1.f / 64.f);
    float v = 0.f;
    for (int j = 0; j < 64; j++) { float x = d[t][j] - m; v += x * x; }
    v *= (1.f / 64.f);
    mrow[t] = m; irow[t] = 1.f / sqrtf(v + 1e-5f);
  }
  __syncthreads();
  for (int i = t; i < 2048; i += 256) {
    const int r = i >> 6, c = i & 63;
    lat[(row0 + r) * 256 + c] = (d[r][c] - mrow[r]) * irow[r] * G[c] + Bn[c];
  }
}

// ---------------- conv1 + conv2, elu, flatten -> bf16 ----------------
// 1 image per block. conv1: thread=(co4,y4) computes 16 x. conv2: thread=(co5,y3) computes 8 x.
__global__ __launch_bounds__(256) void k_conv(
    const float* __restrict__ cam,
    const float* __restrict__ C1W, const float* __restrict__ C1B,
    const float* __restrict__ C2W, const float* __restrict__ C2B,
    unsigned short* __restrict__ flat) {
  __shared__ __align__(16) float img[32 * 34];      // pitch 34, cols 32/33 zero pad
  __shared__ float w1s[144];
  __shared__ __align__(16) float w2s[16 * 32 * 12]; // [ci][co][12] (9 taps + 3 pad)
  __shared__ __align__(16) float c1[16 * 16 * 18];  // [ci][y][18] cols 16/17 zero pad
  const int t = threadIdx.x;
  const size_t b = blockIdx.x;
  {
    const float* ip = cam + b * 1024;
    for (int i = t; i < 1024; i += 256) img[(i >> 5) * 34 + (i & 31)] = ip[i];
    if (t < 64) img[(t & 31) * 34 + 32 + (t >> 5)] = 0.f;  // zero right pad
    if (t < 144) w1s[t] = C1W[t];
    for (int i = t; i < 4608; i += 256) {
      const int co = i / 144, rem = i % 144, ci = rem / 9, tap = rem % 9;
      w2s[ci * 384 + co * 12 + tap] = C2W[i];
    }
  }
  __syncthreads();
  {  // conv1
    const int c = t >> 4, y = t & 15;
    float acc[16];
    #pragma unroll
    for (int x = 0; x < 16; x++) acc[x] = 0.f;
    #pragma unroll
    for (int dy = 0; dy < 3; dy++) {
      const int row = 2 * y + dy;
      if (row < 32) {
        float2 f[17];
        #pragma unroll
        for (int i = 0; i < 17; i++) f[i] = *(const float2*)&img[row * 34 + 2 * i];
        const float wa = w1s[c * 9 + dy * 3], wb = w1s[c * 9 + dy * 3 + 1], wc = w1s[c * 9 + dy * 3 + 2];
        #pragma unroll
        for (int x = 0; x < 16; x++) acc[x] += wa * f[x].x + wb * f[x].y + wc * f[x + 1].x;
      }
    }
    const float bb = C1B[c];
    #pragma unroll
    for (int x = 0; x < 8; x++) {
      float2 v;
      v.x = elu_f(acc[2 * x] + bb);
      v.y = elu_f(acc[2 * x + 1] + bb);
      *(float2*)&c1[c * 288 + y * 18 + 2 * x] = v;
    }
    *(float2*)&c1[c * 288 + y * 18 + 16] = make_float2(0.f, 0.f);  // zero pad
  }
  __syncthreads();
  {  // conv2
    const int co = t >> 3, y = t & 7;
    float acc[8];
    #pragma unroll
    for (int x = 0; x < 8; x++) acc[x] = 0.f;
    for (int ci = 0; ci < 16; ci++) {
      const float4 wv0 = *(const float4*)&w2s[ci * 384 + co * 12];
      const float4 wv1 = *(const float4*)&w2s[ci * 384 + co * 12 + 4];
      const float4 wv2 = *(const float4*)&w2s[ci * 384 + co * 12 + 8];
      const float wk0 = wv0.x, wk1 = wv0.y, wk2 = wv0.z, wk3 = wv0.w;
      const float wk4 = wv1.x, wk5 = wv1.y, wk6 = wv1.z, wk7 = wv1.w, wk8 = wv2.x;
      #pragma unroll
      for (int dy = 0; dy < 3; dy++) {
        const int row = 2 * y + dy;
        if (row < 16) {
          float2 p[9];
          #pragma unroll
          for (int i = 0; i < 9; i++) p[i] = *(const float2*)&c1[ci * 288 + row * 18 + 2 * i];
          const float w0 = dy == 0 ? wk0 : dy == 1 ? wk3 : wk6;
          const float w1 = dy == 0 ? wk1 : dy == 1 ? wk4 : wk7;
          const float w2 = dy == 0 ? wk2 : dy == 1 ? wk5 : wk8;
          #pragma unroll
          for (int x = 0; x < 8; x++)
            acc[x] += w0 * p[x].x + w1 * p[x].y + w2 * p[x + 1].x;
        }
      }
    }
    const float bb = C2B[co];
    u16x8 o;
    #pragma unroll
    for (int x = 0; x < 8; x++) o[x] = f2bf(elu_f(acc[x] + bb));
    *(u16x8*)(flat + b * 2048 + t * 8) = o;  // fully coalesced, [co][y][x] order
  }
}

// ---------------- cnn_lin_w [2048][192] f32 -> Wb [192][2048] bf16 ----------------
__global__ __launch_bounds__(256) void k_cnnw(
    const float* __restrict__ W, unsigned short* __restrict__ Wb) {
  __shared__ float tile[64][65];
  const int t = threadIdx.x;
  const int k0 = blockIdx.x * 64, j0 = blockIdx.y * 64;
  for (int idx = t; idx < 4096; idx += 256) {
    const int kk = idx >> 6, jj = idx & 63;
    tile[kk][jj] = W[(size_t)(k0 + kk) * 192 + j0 + jj];
  }
  __syncthreads();
  for (int idx = t; idx < 4096; idx += 256) {
    const int jj = idx >> 6, kk = idx & 63;
    Wb[(size_t)(j0 + jj) * 2048 + k0 + kk] = f2bf(tile[kk][jj]);
  }
}

// ---------------- cnn linear via MFMA: [64 rows] x [2048] @ Wb^T -> 192, +bias, LN ----------------
__global__ __launch_bounds__(256) void k_cnnlin(
    const unsigned short* __restrict__ Xc, const unsigned short* __restrict__ Wb,
    const float* __restrict__ bias, const float* __restrict__ G,
    const float* __restrict__ Bn, float* __restrict__ lat, int row_base) {
  __shared__ __align__(16) char smem[64 * 196 * 4];  // X stage (32KB) then Y f32 (50.2KB)
  __shared__ float mrow[64], irow[64];
  unsigned short* XS = (unsigned short*)smem;
  float* Yl = (float*)smem;
  const int t = threadIdx.x;
  const int lane = t & 63, w = t >> 6;
  const int lr = lane & 15, lg = lane >> 4;
  const int b0 = blockIdx.x * 64;
  const int j0w = w * 48;

  f32x4 acc[3][4];
  #pragma unroll
  for (int jt = 0; jt < 3; jt++)
    #pragma unroll
    for (int mt = 0; mt < 4; mt++) acc[jt][mt] = (f32x4){0.f, 0.f, 0.f, 0.f};

  int mtb[4];
  #pragma unroll
  for (int mt = 0; mt < 4; mt++) mtb[mt] = (mt * 16 + lr) * 512 + lg * 16;

  for (int kc = 0; kc < 8; kc++) {
    // stage X[64][kc*256 .. +256] bf16 swizzled
    #pragma unroll
    for (int i = 0; i < 8; i++) {
      const int f = t + i * 256;
      const int m = f >> 5;
      const int koff = (f & 31) * 8;
      const u16x8 v = *(const u16x8*)(Xc + (size_t)(b0 + m) * 2048 + kc * 256 + koff);
      *(u16x8*)((char*)XS + swz(m * 512 + koff * 2)) = v;
    }
    __syncthreads();
    const size_t wbase = (size_t)kc * 256;
    #pragma unroll
    for (int ks = 0; ks < 8; ks++) {
      bf16x8 af[3], bfr[4];
      #pragma unroll
      for (int jt = 0; jt < 3; jt++)
        af[jt] = *(const bf16x8*)(Wb + (size_t)(j0w + jt * 16 + lr) * 2048 + wbase + ks * 32 + lg * 8);
      #pragma unroll
      for (int mt = 0; mt < 4; mt++)
        bfr[mt] = *(const bf16x8*)((char*)XS + swz(mtb[mt] + ks * 64));
      #pragma unroll
      for (int jt = 0; jt < 3; jt++)
        #pragma unroll
        for (int mt = 0; mt < 4; mt++)
          acc[jt][mt] = __builtin_amdgcn_mfma_f32_16x16x32_bf16(af[jt], bfr[mt], acc[jt][mt], 0, 0, 0);
    }
    __syncthreads();
  }
  // epilogue: bias, park in LDS f32 [64][196]
  #pragma unroll
  for (int jt = 0; jt < 3; jt++) {
    const int j0 = j0w + jt * 16 + 4 * lg;
    const float4 bb = *(const float4*)(bias + j0);
    #pragma unroll
    for (int mt = 0; mt < 4; mt++) {
      const int m = mt * 16 + lr;
      f32x4 v = acc[jt][mt];
      v[0] += bb.x; v[1] += bb.y; v[2] += bb.z; v[3] += bb.w;
      *(f32x4*)&Yl[m * 196 + j0] = v;
    }
  }
  __syncthreads();
  if (t < 64) {
    float m = 0.f;
    for (int q = 0; q < 48; q++) {
      const f32x4 v = *(const f32x4*)&Yl[t * 196 + q * 4];
      m += v[0] + v[1] + v[2] + v[3];
    }
    m *= (1.f / 192.f);
    float var = 0.f;
    for (int q = 0; q < 48; q++) {
      const f32x4 v = *(const f32x4*)&Yl[t * 196 + q * 4];
      #pragma unroll
      for (int z = 0; z < 4; z++) { const float x = v[z] - m; var += x * x; }
    }
    var *= (1.f / 192.f);
    mrow[t] = m; irow[t] = 1.f / sqrtf(var + 1e-5f);
  }
  __syncthreads();
  for (int i = t; i < 3072; i += 256) {  // 64 rows x 48 f32x4
    const int m = i / 48, q = i % 48;
    const f32x4 v = *(const f32x4*)&Yl[m * 196 + q * 4];
    const float4 gg = *(const float4*)&G[q * 4];
    const float4 bb = *(const float4*)&Bn[q * 4];
    const float mm = mrow[m], iv = irow[m];
    float4 o;
    o.x = (v[0] - mm) * iv * gg.x + bb.x;
    o.y = (v[1] - mm) * iv * gg.y + bb.y;
    o.z = (v[2] - mm) * iv * gg.z + bb.z;
    o.w = (v[3] - mm) * iv * gg.w + bb.w;
    *(float4*)&lat[(size_t)(row_base + b0 + m) * 256 + 64 + q * 4] = o;
  }
}

// ---------------- router ----------------
__global__ __launch_bounds__(256) void k_router(
    const float* __restrict__ lat,
    const float* __restrict__ W1, const float* __restrict__ B1,
    const float* __restrict__ W2, const float* __restrict__ B2,
    const float* __restrict__ W3, const float* __restrict__ B3,
    float* __restrict__ gate) {
  __shared__ __align__(16) float a[32][256];
  __shared__ float h1[32][128];
  __shared__ float h2[32][64];
  __shared__ float lg[32][16];
  const int t = threadIdx.x;
  const size_t row0 = (size_t)blockIdx.x * 32;
  {
    const float4* s = (const float4*)(lat + row0 * 256);
    float4* dd = (float4*)&a[0][0];
    #pragma unroll
    for (int i = 0; i < 8; i++) dd[t + i * 256] = s[t + i * 256];
  }
  __syncthreads();
  {
    const int c = t & 127, g0 = (t >> 7) * 16;
    float acc[16];
    #pragma unroll
    for (int i = 0; i < 16; i++) acc[i] = 0.f;
    for (int k = 0; k < 256; k++) {
      const float w = W1[k * 128 + c];
      #pragma unroll
      for (int i = 0; i < 16; i++) acc[i] += a[g0 + i][k] * w;
    }
    const float bb = B1[c];
    #pragma unroll
    for (int i = 0; i < 16; i++) h1[g0 + i][c] = elu_f(acc[i] + bb);
  }
  __syncthreads();
  {
    const int c = t & 63, g0 = (t >> 6) * 8;
    float acc[8];
    #pragma unroll
    for (int i = 0; i < 8; i++) acc[i] = 0.f;
    for (int k = 0; k < 128; k++) {
      const float w = W2[k * 64 + c];
      #pragma unroll
      for (int i = 0; i < 8; i++) acc[i] += h1[g0 + i][k] * w;
    }
    const float bb = B2[c];
    #pragma unroll
    for (int i = 0; i < 8; i++) h2[g0 + i][c] = elu_f(acc[i] + bb);
  }
  __syncthreads();
  for (int o = t; o < 512; o += 256) {
    const int r = o >> 4, c = o & 15;
    float acc = 0.f;
    for (int k = 0; k < 64; k++) acc += h2[r][k] * W3[k * 16 + c];
    lg[r][c] = acc + B3[c];
  }
  __syncthreads();
  if (t < 32) {
    float m = lg[t][0];
    for (int c = 1; c < 16; c++) m = fmaxf(m, lg[t][c]);
    float s = 0.f;
    float ex[16];
    for (int c = 0; c < 16; c++) { ex[c] = expf(lg[t][c] - m); s += ex[c]; }
    const float inv = 1.f / s;
    for (int c = 0; c < 16; c++) gate[(row0 + t) * 16 + c] = ex[c] * inv;
  }
}

// ---------------- expert weight transpose+convert ----------------
__global__ __launch_bounds__(256) void k_wt(
    const float* __restrict__ ew1, const float* __restrict__ ew2, const float* __restrict__ ew3,
    unsigned short* __restrict__ wt1, unsigned short* __restrict__ wt2, unsigned short* __restrict__ wt3) {
  __shared__ float tile[64][65];
  const int t = threadIdx.x;
  const int zl = blockIdx.z;
  const int layer = zl >> 4, e = zl & 15;
  const float* src = (layer == 0 ? ew1 : layer == 1 ? ew2 : ew3) + (size_t)e * 65536;
  unsigned short* dst = (layer == 0 ? wt1 : layer == 1 ? wt2 : wt3) + (size_t)e * 65536;
  const int k0 = blockIdx.x * 64, j0 = blockIdx.y * 64;
  for (int idx = t; idx < 4096; idx += 256) {
    const int kk = idx >> 6, jj = idx & 63;
    tile[kk][jj] = src[(size_t)(k0 + kk) * 256 + j0 + jj];
  }
  __syncthreads();
  for (int idx = t; idx < 4096; idx += 256) {
    const int jj = idx >> 6, kk = idx & 63;
    dst[(size_t)(j0 + jj) * 256 + k0 + kk] = f2bf(tile[kk][jj]);
  }
}

__global__ __launch_bounds__(256) void k_w4t(
    const float* __restrict__ ew4, unsigned short* __restrict__ w4t) {
  const int e = blockIdx.x, k = threadIdx.x;
  #pragma unroll
  for (int j = 0; j < 16; j++) {
    const float v = (j < 12) ? ew4[(size_t)e * 3072 + k * 12 + j] : 0.f;
    w4t[(size_t)e * 4096 + j * 256 + k] = f2bf(v);
  }
}

// ---------------- experts: bf16 MFMA fused 4-layer MLP (unchanged control) ----------------
__global__ __launch_bounds__(256) void k_experts(
    const float* __restrict__ lat, const float* __restrict__ gate,
    const unsigned short* __restrict__ wt1, const unsigned short* __restrict__ wt2,
    const unsigned short* __restrict__ wt3, const unsigned short* __restrict__ w4t,
    const float* __restrict__ EB1, const float* __restrict__ EB2,
    const float* __restrict__ EB3, const float* __restrict__ EB4,
    float* __restrict__ eout) {
  __shared__ __align__(16) unsigned short X[64 * 256];
  char* xb = (char*)X;
  const int t = threadIdx.x;
  const int lane = t & 63, w = t >> 6;
  const int lr = lane & 15, lg = lane >> 4;
  const int e = blockIdx.y;
  const int row0 = blockIdx.x * 64;

  #pragma unroll
  for (int i = 0; i < 16; i++) {
    const int f = t + i * 256;
    const int m = f >> 6;
    const int k0 = (f & 63) * 4;
    const float4 v = *(const float4*)(lat + (size_t)(row0 + m) * 256 + k0);
    ushort4 h;
    h.x = f2bf(v.x); h.y = f2bf(v.y); h.z = f2bf(v.z); h.w = f2bf(v.w);
    *(ushort4*)(xb + swz(m * 512 + k0 * 2)) = h;
  }
  __syncthreads();

  const unsigned short* Wl[3] = {
    wt1 + (size_t)e * 65536, wt2 + (size_t)e * 65536, wt3 + (size_t)e * 65536 };
  const float* Bl[3] = { EB1 + e * 256, EB2 + e * 256, EB3 + e * 256 };
  const int wjb = w * 64;

  int mtb[4];
  #pragma unroll
  for (int mt = 0; mt < 4; mt++) mtb[mt] = (mt * 16 + lr) * 512 + lg * 16;

  #pragma unroll
  for (int l = 0; l < 3; l++) {
    const unsigned short* W = Wl[l];
    f32x4 acc[4][4];
    #pragma unroll
    for (int jt = 0; jt < 4; jt++)
      #pragma unroll
      for (int mt = 0; mt < 4; mt++) acc[jt][mt] = (f32x4){0.f, 0.f, 0.f, 0.f};
    const size_t wlane = (size_t)(wjb + lr) * 256 + lg * 8;
    for (int ks = 0; ks < 8; ks++) {
      bf16x8 af[4], bfr[4];
      #pragma unroll
      for (int jt = 0; jt < 4; jt++)
        af[jt] = *(const bf16x8*)(W + wlane + jt * 4096 + ks * 32);
      #pragma unroll
      for (int mt = 0; mt < 4; mt++)
        bfr[mt] = *(const bf16x8*)(xb + swz(mtb[mt] + ks * 64));
      #pragma unroll
      for (int jt = 0; jt < 4; jt++)
        #pragma unroll
        for (int mt = 0; mt < 4; mt++)
          acc[jt][mt] = __builtin_amdgcn_mfma_f32_16x16x32_bf16(af[jt], bfr[mt], acc[jt][mt], 0, 0, 0);
    }
    __syncthreads();
    const float* B = Bl[l];
    #pragma unroll
    for (int jt = 0; jt < 4; jt++) {
      const int j0 = wjb + jt * 16 + 4 * lg;
      const float4 bb = *(const float4*)(B + j0);
      #pragma unroll
      for (int mt = 0; mt < 4; mt++) {
        const int m = mt * 16 + lr;
        ushort4 h;
        h.x = f2bf(elu_fast(acc[jt][mt][0] + bb.x));
        h.y = f2bf(elu_fast(acc[jt][mt][1] + bb.y));
        h.z = f2bf(elu_fast(acc[jt][mt][2] + bb.z));
        h.w = f2bf(elu_fast(acc[jt][mt][3] + bb.w));
        *(ushort4*)(xb + swz(m * 512 + j0 * 2)) = h;
      }
    }
    __syncthreads();
  }

  {
    const unsigned short* W4 = w4t + (size_t)e * 4096;
    f32x4 a4 = (f32x4){0.f, 0.f, 0.f, 0.f};
    const size_t wl4 = (size_t)lr * 256 + lg * 8;
    const int mb = (w * 16 + lr) * 512 + lg * 16;
    for (int ks = 0; ks < 8; ks++) {
      const bf16x8 a = *(const bf16x8*)(W4 + wl4 + ks * 32);
      const bf16x8 b = *(const bf16x8*)(xb + swz(mb + ks * 64));
      a4 = __builtin_amdgcn_mfma_f32_16x16x32_bf16(a, b, a4, 0, 0, 0);
    }
    const int row = row0 + w * 16 + lr;
    const float gv = gate[(size_t)row * 16 + e];
    if (lg < 3) {
      const float4 bb = *(const float4*)(EB4 + e * 12 + 4 * lg);
      float4 o;
      o.x = gv * (a4[0] + bb.x);
      o.y = gv * (a4[1] + bb.y);
      o.z = gv * (a4[2] + bb.z);
      o.w = gv * (a4[3] + bb.w);
      *(float4*)(eout + ((size_t)e * BATCH + row) * 12 + 4 * lg) = o;
    }
  }
}

__global__ __launch_bounds__(256) void k_reduce(
    const float* __restrict__ eout, float* __restrict__ out) {
  const int i = blockIdx.x * 256 + threadIdx.x;
  if (i < BATCH * OUTD) {
    float s = 0.f;
    #pragma unroll
    for (int e = 0; e < NE; e++) s += eout[(size_t)e * (BATCH * OUTD) + i];
    out[i] = s;
  }
}

extern "C" void kernel_launch(void* const* d_in, const int* in_sizes, int n_in,
                              void* d_out, int out_size, void* d_ws, size_t ws_size,
                              hipStream_t stream) {
  (void)in_sizes; (void)n_in; (void)out_size; (void)ws_size;
  const float* proprio   = (const float*)d_in[0];
  const float* camera    = (const float*)d_in[1];
  const float* enc_w1    = (const float*)d_in[2];
  const float* enc_b1    = (const float*)d_in[3];
  const float* enc_w2    = (const float*)d_in[4];
  const float* enc_b2    = (const float*)d_in[5];
  const float* enc_ln_g  = (const float*)d_in[6];
  const float* enc_ln_b  = (const float*)d_in[7];
  const float* conv1_w   = (const float*)d_in[8];
  const float* conv1_b   = (const float*)d_in[9];
  const float* conv2_w   = (const float*)d_in[10];
  const float* conv2_b   = (const float*)d_in[11];
  const float* cnn_lin_w = (const float*)d_in[12];
  const float* cnn_lin_b = (const float*)d_in[13];
  const float* cnn_ln_g  = (const float*)d_in[14];
  const float* cnn_ln_b  = (const float*)d_in[15];
  const float* rw1 = (const float*)d_in[16];
  const float* rb1 = (const float*)d_in[17];
  const float* rw2 = (const float*)d_in[18];
  const float* rb2 = (const float*)d_in[19];
  const float* rw3 = (const float*)d_in[20];
  const float* rb3 = (const float*)d_in[21];
  const float* ew1 = (const float*)d_in[22];
  const float* eb1 = (const float*)d_in[23];
  const float* ew2 = (const float*)d_in[24];
  const float* eb2 = (const float*)d_in[25];
  const float* ew3 = (const float*)d_in[26];
  const float* eb3 = (const float*)d_in[27];
  const float* ew4 = (const float*)d_in[28];
  const float* eb4 = (const float*)d_in[29];
  float* out = (float*)d_out;

  // ws: lat f32 | gate f32 | eout f32 | wt1-3 bf16 | w4t bf16 | cnnWb bf16 | convflat bf16
  float* lat  = (float*)d_ws;
  float* gate = lat + (size_t)BATCH * LATD;
  float* eout = gate + (size_t)BATCH * NE;
  unsigned short* wt1 = (unsigned short*)(eout + (size_t)NE * BATCH * OUTD);
  unsigned short* wt2 = wt1 + (size_t)NE * 65536;
  unsigned short* wt3 = wt2 + (size_t)NE * 65536;
  unsigned short* w4t = wt3 + (size_t)NE * 65536;
  unsigned short* cnnWb = w4t + (size_t)NE * 4096;
  unsigned short* convflat = cnnWb + (size_t)192 * 2048;

  k_wt<<<dim3(4, 4, 48), dim3(256), 0, stream>>>(ew1, ew2, ew3, wt1, wt2, wt3);
  k_w4t<<<dim3(16), dim3(256), 0, stream>>>(ew4, w4t);
  k_cnnw<<<dim3(32, 3), dim3(256), 0, stream>>>(cnn_lin_w, cnnWb);
  k_proprio<<<dim3(512), dim3(256), 0, stream>>>(proprio, enc_w1, enc_b1, enc_w2, enc_b2,
                                                 enc_ln_g, enc_ln_b, lat);
  for (int ch = 0; ch < 2; ch++) {
    k_conv<<<dim3(8192), dim3(256), 0, stream>>>(camera + (size_t)ch * 8192 * 1024,
                                                 conv1_w, conv1_b, conv2_w, conv2_b, convflat);
    k_cnnlin<<<dim3(128), dim3(256), 0, stream>>>(convflat, cnnWb, cnn_lin_b,
                                                  cnn_ln_g, cnn_ln_b, lat, ch * 8192);
  }
  k_router<<<dim3(512), dim3(256), 0, stream>>>(lat, rw1, rb1, rw2, rb2, rw3, rb3, gate);
  k_experts<<<dim3(256, 16), dim3(256), 0, stream>>>(lat, gate, wt1, wt2, wt3, w4t,
                                                     eb1, eb2, eb3, eb4, eout);
  k_reduce<<<dim3(768), dim3(256), 0, stream>>>(eout, out);
}

// Round 4
// 637.122 us; speedup vs baseline: 3.9487x; 1.2780x over previous
//
#include <hip/hip_runtime.h>
#include <math.h>

#define BATCH 16384
#define LATD 256
#define OUTD 12
#define NE 16

typedef short bf16x8 __attribute__((ext_vector_type(8)));
typedef float f32x4 __attribute__((ext_vector_type(4)));
typedef unsigned short u16x8 __attribute__((ext_vector_type(8)));

__device__ __forceinline__ float elu_f(float x) { return x > 0.f ? x : expm1f(x); }
__device__ __forceinline__ float elu_fast(float x) { return x > 0.f ? x : (__expf(x) - 1.f); }

__device__ __forceinline__ unsigned short f2bf(float f) {
  union { float f; unsigned int u; } a; a.f = f;
  unsigned int u = a.u;
  unsigned int r = (u + 0x7FFFu + ((u >> 16) & 1u)) >> 16;
  return (unsigned short)r;
}
__device__ __forceinline__ float bf2f(unsigned short h) {
  union { unsigned int u; float f; } a; a.u = ((unsigned int)h) << 16;
  return a.f;
}

// XOR swizzle on byte address within a 512B-row tile (bank-conflict fix).
// 16B-granular: safe for any access >= contained in a 16B chunk.
__device__ __forceinline__ int swz(int b) { return b ^ (((b >> 9) & 7) << 4); }

// lat16 layout: tiles of 128 rows; tile rb = row>>7; within tile, byte
// addr = swz((row&127)*512 + col*2). Tile stride 65536 B.

// ---------------- proprio encoder: 256 ->128 elu ->64 + LN -> lat16 cols 0..63 ----------------
__global__ __launch_bounds__(256) void k_proprio(
    const float* __restrict__ P,
    const float* __restrict__ W1, const float* __restrict__ B1,
    const float* __restrict__ W2, const float* __restrict__ B2,
    const float* __restrict__ G, const float* __restrict__ Bn,
    unsigned short* __restrict__ lat16) {
  __shared__ __align__(16) float a[32][256];
  __shared__ float h[32][128];
  __shared__ float d[32][64];
  __shared__ float mrow[32], irow[32];
  const int t = threadIdx.x;
  const size_t row0 = (size_t)blockIdx.x * 32;
  {
    const float4* s = (const float4*)(P + row0 * 256);
    float4* dd = (float4*)&a[0][0];
    #pragma unroll
    for (int i = 0; i < 8; i++) dd[t + i * 256] = s[t + i * 256];
  }
  __syncthreads();
  {
    const int c = t & 127, g0 = (t >> 7) * 16;
    float acc[16];
    #pragma unroll
    for (int i = 0; i < 16; i++) acc[i] = 0.f;
    for (int k = 0; k < 256; k++) {
      const float w = W1[k * 128 + c];
      #pragma unroll
      for (int i = 0; i < 16; i++) acc[i] += a[g0 + i][k] * w;
    }
    const float bb = B1[c];
    #pragma unroll
    for (int i = 0; i < 16; i++) h[g0 + i][c] = elu_f(acc[i] + bb);
  }
  __syncthreads();
  {
    const int c = t & 63, g0 = (t >> 6) * 8;
    float acc[8];
    #pragma unroll
    for (int i = 0; i < 8; i++) acc[i] = 0.f;
    for (int k = 0; k < 128; k++) {
      const float w = W2[k * 64 + c];
      #pragma unroll
      for (int i = 0; i < 8; i++) acc[i] += h[g0 + i][k] * w;
    }
    const float bb = B2[c];
    #pragma unroll
    for (int i = 0; i < 8; i++) d[g0 + i][c] = acc[i] + bb;
  }
  __syncthreads();
  if (t < 32) {
    float m = 0.f;
    for (int j = 0; j < 64; j++) m += d[t][j];
    m *= (1.f / 64.f);
    float v = 0.f;
    for (int j = 0; j < 64; j++) { float x = d[t][j] - m; v += x * x; }
    v *= (1.f / 64.f);
    mrow[t] = m; irow[t] = 1.f / sqrtf(v + 1e-5f);
  }
  __syncthreads();
  {  // 32 rows x 8 chunks of 8 cols -> swizzled bf16 store
    const int r = t >> 3, ch = t & 7;
    const size_t grow = row0 + r;
    const size_t rb = grow >> 7;
    const int loc = (int)(grow & 127);
    u16x8 o;
    #pragma unroll
    for (int q = 0; q < 8; q++) {
      const int c = ch * 8 + q;
      o[q] = f2bf((d[r][c] - mrow[r]) * irow[r] * G[c] + Bn[c]);
    }
    *(u16x8*)((char*)lat16 + rb * 65536 + swz(loc * 512 + ch * 16)) = o;
  }
}

// ---------------- conv2 weight prep: C2W [co][ci][3][3] f32 -> w2g bf16 [co][ci*16+tap] ----------------
__global__ __launch_bounds__(256) void k_w2c(
    const float* __restrict__ C2W, unsigned short* __restrict__ w2g) {
  const int t = threadIdx.x;
  const int co = t >> 3, ci0 = t & 7;
  #pragma unroll
  for (int hh = 0; hh < 2; hh++) {
    const int ci = ci0 + hh * 8;
    #pragma unroll
    for (int tap = 0; tap < 16; tap++) {
      w2g[co * 256 + ci * 16 + tap] =
          (tap < 9) ? f2bf(C2W[co * 144 + ci * 9 + tap]) : (unsigned short)0;
    }
  }
}

// ---------------- conv1 (VALU) + conv2 (implicit-GEMM MFMA), flatten -> bf16 ----------------
__global__ __launch_bounds__(256) void k_conv(
    const float* __restrict__ cam,
    const float* __restrict__ C1W, const float* __restrict__ C1B,
    const unsigned short* __restrict__ w2g, const float* __restrict__ C2B,
    unsigned short* __restrict__ flat) {
  __shared__ __align__(16) float img[32 * 36];          // pitch 36, cols 32-35 zero
  __shared__ float w1s[144];
  __shared__ __align__(16) unsigned short c1[16 * 17 * 20];  // [ci][17 rows][20 cols] bf16, row16 + cols16-19 zero
  __shared__ __align__(16) unsigned short Bm[64 * 256];      // im2col B, swizzled, 32KB
  __shared__ __align__(16) unsigned short obuf[2048];
  const int t = threadIdx.x;
  const int lane = t & 63, w = t >> 6;
  const int lr = lane & 15, lg = lane >> 4;
  const size_t b = blockIdx.x;
  char* c1b = (char*)c1;
  char* bmb = (char*)Bm;
  {
    const float* ip = cam + b * 1024;
    for (int i = t; i < 1024; i += 256) img[(i >> 5) * 36 + (i & 31)] = ip[i];
    if (t < 32) *(float4*)&img[t * 36 + 32] = make_float4(0.f, 0.f, 0.f, 0.f);
    if (t < 144) w1s[t] = C1W[t];
    if (t < 80) *(ushort4*)(c1b + (t / 5) * 680 + 640 + (t % 5) * 8) = make_ushort4(0, 0, 0, 0);  // zero row 16
  }
  __syncthreads();
  {  // conv1: thread=(co c, row y), 16 x outputs -> c1 bf16
    const int c = t >> 4, y = t & 15;
    float acc[16];
    #pragma unroll
    for (int x = 0; x < 16; x++) acc[x] = 0.f;
    #pragma unroll
    for (int dy = 0; dy < 3; dy++) {
      const int row = 2 * y + dy;
      if (row < 32) {
        float4 f4[9];
        #pragma unroll
        for (int i = 0; i < 9; i++) f4[i] = *(const float4*)&img[row * 36 + 4 * i];
        const float* rr = (const float*)f4;
        const float wa = w1s[c * 9 + dy * 3], wb = w1s[c * 9 + dy * 3 + 1], wc = w1s[c * 9 + dy * 3 + 2];
        #pragma unroll
        for (int x = 0; x < 16; x++) acc[x] += wa * rr[2 * x] + wb * rr[2 * x + 1] + wc * rr[2 * x + 2];
      }
    }
    const float bb = C1B[c];
    #pragma unroll
    for (int p = 0; p < 4; p++) {
      ushort4 v;
      v.x = f2bf(elu_fast(acc[4 * p + 0] + bb));
      v.y = f2bf(elu_fast(acc[4 * p + 1] + bb));
      v.z = f2bf(elu_fast(acc[4 * p + 2] + bb));
      v.w = f2bf(elu_fast(acc[4 * p + 3] + bb));
      *(ushort4*)(c1b + c * 680 + y * 40 + p * 8) = v;
    }
    *(ushort4*)(c1b + c * 680 + y * 40 + 32) = make_ushort4(0, 0, 0, 0);  // cols 16-19 zero
  }
  __syncthreads();
  {  // im2col: item=(ci, m=(y,x)) -> B[m][ci*16 + tap(0..8)], taps 9-15 zero
    #pragma unroll
    for (int i = 0; i < 4; i++) {
      const int item = i * 256 + t;
      const int m = item & 63, ci = item >> 6;
      const int y = m >> 3, x = m & 7;
      unsigned int pr[3]; unsigned short th[3];
      #pragma unroll
      for (int dy = 0; dy < 3; dy++) {
        const int base = ci * 680 + (2 * y + dy) * 40 + 4 * x;
        pr[dy] = *(const unsigned int*)(c1b + base);
        th[dy] = *(const unsigned short*)(c1b + base + 4);
      }
      uint4 u0;
      u0.x = pr[0];
      u0.y = ((unsigned int)th[0]) | (((unsigned int)(pr[1] & 0xFFFFu)) << 16);
      u0.z = (pr[1] >> 16) | (((unsigned int)th[1]) << 16);
      u0.w = pr[2];
      uint4 u1;
      u1.x = (unsigned int)th[2];
      u1.y = 0; u1.z = 0; u1.w = 0;
      const int bb0 = m * 512 + ci * 32;
      *(uint4*)(bmb + swz(bb0)) = u0;
      *(uint4*)(bmb + swz(bb0 + 16)) = u1;
    }
  }
  __syncthreads();
  {  // GEMM: out[co 32][m 64] = w2g . B^T ; wave w owns m-tile w, both co-tiles
    f32x4 acc[2];
    acc[0] = (f32x4){0.f, 0.f, 0.f, 0.f};
    acc[1] = (f32x4){0.f, 0.f, 0.f, 0.f};
    const int mbase = (w * 16 + lr) * 512 + lg * 16;
    #pragma unroll
    for (int ks = 0; ks < 8; ks++) {
      const bf16x8 bfr = *(const bf16x8*)(bmb + swz(mbase + ks * 64));
      #pragma unroll
      for (int nt = 0; nt < 2; nt++) {
        const bf16x8 af = *(const bf16x8*)(w2g + (nt * 16 + lr) * 256 + ks * 32 + lg * 8);
        acc[nt] = __builtin_amdgcn_mfma_f32_16x16x32_bf16(af, bfr, acc[nt], 0, 0, 0);
      }
    }
    #pragma unroll
    for (int nt = 0; nt < 2; nt++) {
      const float4 bb = *(const float4*)(C2B + nt * 16 + 4 * lg);
      const float bv[4] = { bb.x, bb.y, bb.z, bb.w };
      #pragma unroll
      for (int q = 0; q < 4; q++) {
        const int co = nt * 16 + 4 * lg + q;
        obuf[co * 64 + w * 16 + lr] = f2bf(elu_fast(acc[nt][q] + bv[q]));
      }
    }
  }
  __syncthreads();
  *(u16x8*)(flat + b * 2048 + t * 8) = *(const u16x8*)(obuf + t * 8);
}

// ---------------- cnn_lin_w [2048][192] f32 -> Wb [192][2048] bf16 ----------------
__global__ __launch_bounds__(256) void k_cnnw(
    const float* __restrict__ W, unsigned short* __restrict__ Wb) {
  __shared__ float tile[64][65];
  const int t = threadIdx.x;
  const int k0 = blockIdx.x * 64, j0 = blockIdx.y * 64;
  for (int idx = t; idx < 4096; idx += 256) {
    const int kk = idx >> 6, jj = idx & 63;
    tile[kk][jj] = W[(size_t)(k0 + kk) * 192 + j0 + jj];
  }
  __syncthreads();
  for (int idx = t; idx < 4096; idx += 256) {
    const int jj = idx >> 6, kk = idx & 63;
    Wb[(size_t)(j0 + jj) * 2048 + k0 + kk] = f2bf(tile[kk][jj]);
  }
}

// ---------------- cnn linear via MFMA: BM=32, +bias, LN -> lat16 cols 64..255 ----------------
__global__ __launch_bounds__(256) void k_cnnlin(
    const unsigned short* __restrict__ Xc, const unsigned short* __restrict__ Wb,
    const float* __restrict__ bias, const float* __restrict__ G,
    const float* __restrict__ Bn, unsigned short* __restrict__ lat16, int row_base) {
  __shared__ __align__(16) unsigned short XS[32 * 256];  // 16KB swizzled
  __shared__ __align__(16) float Yl[32 * 196];
  __shared__ float mrow[32], irow[32];
  char* xsb = (char*)XS;
  const int t = threadIdx.x;
  const int lane = t & 63, w = t >> 6;
  const int lr = lane & 15, lg = lane >> 4;
  const int b0 = blockIdx.x * 32;
  const int j0w = w * 48;

  f32x4 acc[3][2];
  #pragma unroll
  for (int jt = 0; jt < 3; jt++)
    #pragma unroll
    for (int mt = 0; mt < 2; mt++) acc[jt][mt] = (f32x4){0.f, 0.f, 0.f, 0.f};

  for (int kc = 0; kc < 8; kc++) {
    #pragma unroll
    for (int i = 0; i < 4; i++) {
      const int f = t + i * 256;
      const int m = f >> 5;
      const int kof = (f & 31) * 8;
      const u16x8 v = *(const u16x8*)(Xc + (size_t)(b0 + m) * 2048 + kc * 256 + kof);
      *(u16x8*)(xsb + swz(m * 512 + kof * 2)) = v;
    }
    __syncthreads();
    #pragma unroll
    for (int ks = 0; ks < 8; ks++) {
      bf16x8 af[3], bfr[2];
      #pragma unroll
      for (int jt = 0; jt < 3; jt++)
        af[jt] = *(const bf16x8*)(Wb + (size_t)(j0w + jt * 16 + lr) * 2048 + kc * 256 + ks * 32 + lg * 8);
      #pragma unroll
      for (int mt = 0; mt < 2; mt++)
        bfr[mt] = *(const bf16x8*)(xsb + swz((mt * 16 + lr) * 512 + lg * 16 + ks * 64));
      #pragma unroll
      for (int jt = 0; jt < 3; jt++)
        #pragma unroll
        for (int mt = 0; mt < 2; mt++)
          acc[jt][mt] = __builtin_amdgcn_mfma_f32_16x16x32_bf16(af[jt], bfr[mt], acc[jt][mt], 0, 0, 0);
    }
    __syncthreads();
  }
  #pragma unroll
  for (int jt = 0; jt < 3; jt++) {
    const int j0 = j0w + jt * 16 + 4 * lg;
    const float4 bb = *(const float4*)(bias + j0);
    #pragma unroll
    for (int mt = 0; mt < 2; mt++) {
      const int m = mt * 16 + lr;
      f32x4 v = acc[jt][mt];
      v[0] += bb.x; v[1] += bb.y; v[2] += bb.z; v[3] += bb.w;
      *(f32x4*)&Yl[m * 196 + j0] = v;
    }
  }
  __syncthreads();
  if (t < 32) {
    float m = 0.f;
    for (int q = 0; q < 48; q++) {
      const f32x4 v = *(const f32x4*)&Yl[t * 196 + q * 4];
      m += v[0] + v[1] + v[2] + v[3];
    }
    m *= (1.f / 192.f);
    float var = 0.f;
    for (int q = 0; q < 48; q++) {
      const f32x4 v = *(const f32x4*)&Yl[t * 196 + q * 4];
      #pragma unroll
      for (int z = 0; z < 4; z++) { const float x = v[z] - m; var += x * x; }
    }
    var *= (1.f / 192.f);
    mrow[t] = m; irow[t] = 1.f / sqrtf(var + 1e-5f);
  }
  __syncthreads();
  {  // 32 rows x 24 chunks (8 cols each) -> lat16 cols 64..255
    #pragma unroll
    for (int i = 0; i < 3; i++) {
      const int item = t + i * 256;
      const int m = item / 24, cq = item % 24;
      const float mm = mrow[m], iv = irow[m];
      u16x8 o;
      #pragma unroll
      for (int q = 0; q < 8; q++) {
        const int j = cq * 8 + q;
        o[q] = f2bf((Yl[m * 196 + j] - mm) * iv * G[j] + Bn[j]);
      }
      const size_t grow = (size_t)(row_base + b0 + m);
      const size_t rb = grow >> 7;
      const int loc = (int)(grow & 127);
      *(u16x8*)((char*)lat16 + rb * 65536 + swz(loc * 512 + 128 + cq * 16)) = o;
    }
  }
}

// ---------------- router: reads bf16 lat16 ----------------
__global__ __launch_bounds__(256) void k_router(
    const unsigned short* __restrict__ lat16,
    const float* __restrict__ W1, const float* __restrict__ B1,
    const float* __restrict__ W2, const float* __restrict__ B2,
    const float* __restrict__ W3, const float* __restrict__ B3,
    float* __restrict__ gate) {
  __shared__ __align__(16) float a[32][256];
  __shared__ float h1[32][128];
  __shared__ float h2[32][64];
  __shared__ float lg[32][16];
  const int t = threadIdx.x;
  const size_t row0 = (size_t)blockIdx.x * 32;
  {
    #pragma unroll
    for (int i = 0; i < 4; i++) {
      const int cc = t + i * 256;
      const int r = cc >> 5, kc = cc & 31;
      const size_t grow = row0 + r;
      const size_t rb = grow >> 7;
      const int loc = (int)(grow & 127);
      const u16x8 h = *(const u16x8*)((const char*)lat16 + rb * 65536 + swz(loc * 512 + kc * 16));
      #pragma unroll
      for (int q = 0; q < 8; q++) a[r][kc * 8 + q] = bf2f(h[q]);
    }
  }
  __syncthreads();
  {
    const int c = t & 127, g0 = (t >> 7) * 16;
    float acc[16];
    #pragma unroll
    for (int i = 0; i < 16; i++) acc[i] = 0.f;
    for (int k = 0; k < 256; k++) {
      const float w = W1[k * 128 + c];
      #pragma unroll
      for (int i = 0; i < 16; i++) acc[i] += a[g0 + i][k] * w;
    }
    const float bb = B1[c];
    #pragma unroll
    for (int i = 0; i < 16; i++) h1[g0 + i][c] = elu_f(acc[i] + bb);
  }
  __syncthreads();
  {
    const int c = t & 63, g0 = (t >> 6) * 8;
    float acc[8];
    #pragma unroll
    for (int i = 0; i < 8; i++) acc[i] = 0.f;
    for (int k = 0; k < 128; k++) {
      const float w = W2[k * 64 + c];
      #pragma unroll
      for (int i = 0; i < 8; i++) acc[i] += h1[g0 + i][k] * w;
    }
    const float bb = B2[c];
    #pragma unroll
    for (int i = 0; i < 8; i++) h2[g0 + i][c] = elu_f(acc[i] + bb);
  }
  __syncthreads();
  for (int o = t; o < 512; o += 256) {
    const int r = o >> 4, c = o & 15;
    float acc = 0.f;
    for (int k = 0; k < 64; k++) acc += h2[r][k] * W3[k * 16 + c];
    lg[r][c] = acc + B3[c];
  }
  __syncthreads();
  if (t < 32) {
    float m = lg[t][0];
    for (int c = 1; c < 16; c++) m = fmaxf(m, lg[t][c]);
    float s = 0.f;
    float ex[16];
    for (int c = 0; c < 16; c++) { ex[c] = expf(lg[t][c] - m); s += ex[c]; }
    const float inv = 1.f / s;
    for (int c = 0; c < 16; c++) gate[(row0 + t) * 16 + c] = ex[c] * inv;
  }
}

// ---------------- expert weight transpose+convert ----------------
__global__ __launch_bounds__(256) void k_wt(
    const float* __restrict__ ew1, const float* __restrict__ ew2, const float* __restrict__ ew3,
    unsigned short* __restrict__ wt1, unsigned short* __restrict__ wt2, unsigned short* __restrict__ wt3) {
  __shared__ float tile[64][65];
  const int t = threadIdx.x;
  const int zl = blockIdx.z;
  const int layer = zl >> 4, e = zl & 15;
  const float* src = (layer == 0 ? ew1 : layer == 1 ? ew2 : ew3) + (size_t)e * 65536;
  unsigned short* dst = (layer == 0 ? wt1 : layer == 1 ? wt2 : wt3) + (size_t)e * 65536;
  const int k0 = blockIdx.x * 64, j0 = blockIdx.y * 64;
  for (int idx = t; idx < 4096; idx += 256) {
    const int kk = idx >> 6, jj = idx & 63;
    tile[kk][jj] = src[(size_t)(k0 + kk) * 256 + j0 + jj];
  }
  __syncthreads();
  for (int idx = t; idx < 4096; idx += 256) {
    const int jj = idx >> 6, kk = idx & 63;
    dst[(size_t)(j0 + jj) * 256 + k0 + kk] = f2bf(tile[kk][jj]);
  }
}

__global__ __launch_bounds__(256) void k_w4t(
    const float* __restrict__ ew4, unsigned short* __restrict__ w4t) {
  const int e = blockIdx.x, k = threadIdx.x;
  #pragma unroll
  for (int j = 0; j < 16; j++) {
    const float v = (j < 12) ? ew4[(size_t)e * 3072 + k * 12 + j] : 0.f;
    w4t[(size_t)e * 4096 + j * 256 + k] = f2bf(v);
  }
}

// ---------------- experts: BM=128, e-fastest grid, bf16 MFMA fused 4-layer MLP ----------------
__global__ __launch_bounds__(256, 2) void k_experts(
    const unsigned short* __restrict__ lat16, const float* __restrict__ gate,
    const unsigned short* __restrict__ wt1, const unsigned short* __restrict__ wt2,
    const unsigned short* __restrict__ wt3, const unsigned short* __restrict__ w4t,
    const float* __restrict__ EB1, const float* __restrict__ EB2,
    const float* __restrict__ EB3, const float* __restrict__ EB4,
    float* __restrict__ eout) {
  __shared__ __align__(16) unsigned short X[128 * 256];  // 64KB swizzled
  char* xb = (char*)X;
  const int t = threadIdx.x;
  const int lane = t & 63, w = t >> 6;
  const int lr = lane & 15, lg = lane >> 4;
  const int e = blockIdx.x;       // fastest -> 16 consecutive blocks share lat tile
  const int rb = blockIdx.y;
  const int row0 = rb * 128;

  {  // stage: straight 64KB copy (source already swizzled)
    const uint4* s = (const uint4*)(lat16 + (size_t)rb * 32768);
    uint4* dd = (uint4*)X;
    #pragma unroll
    for (int i = 0; i < 16; i++) dd[t + i * 256] = s[t + i * 256];
  }
  __syncthreads();

  const unsigned short* Wl[3] = {
    wt1 + (size_t)e * 65536, wt2 + (size_t)e * 65536, wt3 + (size_t)e * 65536 };
  const float* Bl[3] = { EB1 + e * 256, EB2 + e * 256, EB3 + e * 256 };
  const int wjb = w * 64;

  int mtb[8];
  #pragma unroll
  for (int mt = 0; mt < 8; mt++) mtb[mt] = (mt * 16 + lr) * 512 + lg * 16;

  #pragma unroll
  for (int l = 0; l < 3; l++) {
    const unsigned short* W = Wl[l];
    f32x4 acc[4][8];
    #pragma unroll
    for (int jt = 0; jt < 4; jt++)
      #pragma unroll
      for (int mt = 0; mt < 8; mt++) acc[jt][mt] = (f32x4){0.f, 0.f, 0.f, 0.f};
    const size_t wlane = (size_t)(wjb + lr) * 256 + lg * 8;
    for (int ks = 0; ks < 8; ks++) {
      bf16x8 af[4], bfr[8];
      #pragma unroll
      for (int jt = 0; jt < 4; jt++)
        af[jt] = *(const bf16x8*)(W + wlane + jt * 4096 + ks * 32);
      #pragma unroll
      for (int mt = 0; mt < 8; mt++)
        bfr[mt] = *(const bf16x8*)(xb + swz(mtb[mt] + ks * 64));
      #pragma unroll
      for (int jt = 0; jt < 4; jt++)
        #pragma unroll
        for (int mt = 0; mt < 8; mt++)
          acc[jt][mt] = __builtin_amdgcn_mfma_f32_16x16x32_bf16(af[jt], bfr[mt], acc[jt][mt], 0, 0, 0);
    }
    __syncthreads();  // all reads of X done
    const float* B = Bl[l];
    #pragma unroll
    for (int jt = 0; jt < 4; jt++) {
      const int j0 = wjb + jt * 16 + 4 * lg;
      const float4 bb = *(const float4*)(B + j0);
      #pragma unroll
      for (int mt = 0; mt < 8; mt++) {
        const int m = mt * 16 + lr;
        ushort4 h;
        h.x = f2bf(elu_fast(acc[jt][mt][0] + bb.x));
        h.y = f2bf(elu_fast(acc[jt][mt][1] + bb.y));
        h.z = f2bf(elu_fast(acc[jt][mt][2] + bb.z));
        h.w = f2bf(elu_fast(acc[jt][mt][3] + bb.w));
        *(ushort4*)(xb + swz(m * 512 + j0 * 2)) = h;
      }
    }
    __syncthreads();
  }

  {  // layer 4: wave handles m-tiles 2w, 2w+1
    const unsigned short* W4 = w4t + (size_t)e * 4096;
    f32x4 a4[2];
    a4[0] = (f32x4){0.f, 0.f, 0.f, 0.f};
    a4[1] = (f32x4){0.f, 0.f, 0.f, 0.f};
    const size_t wl4 = (size_t)lr * 256 + lg * 8;
    #pragma unroll
    for (int ks = 0; ks < 8; ks++) {
      const bf16x8 a = *(const bf16x8*)(W4 + wl4 + ks * 32);
      #pragma unroll
      for (int hh = 0; hh < 2; hh++) {
        const bf16x8 bv = *(const bf16x8*)(xb + swz(mtb[2 * w + hh] + ks * 64));
        a4[hh] = __builtin_amdgcn_mfma_f32_16x16x32_bf16(a, bv, a4[hh], 0, 0, 0);
      }
    }
    if (lg < 3) {
      const float4 bb = *(const float4*)(EB4 + e * 12 + 4 * lg);
      #pragma unroll
      for (int hh = 0; hh < 2; hh++) {
        const int row = row0 + (2 * w + hh) * 16 + lr;
        const float gv = gate[(size_t)row * 16 + e];
        float4 o;
        o.x = gv * (a4[hh][0] + bb.x);
        o.y = gv * (a4[hh][1] + bb.y);
        o.z = gv * (a4[hh][2] + bb.z);
        o.w = gv * (a4[hh][3] + bb.w);
        *(float4*)(eout + ((size_t)e * BATCH + row) * 12 + 4 * lg) = o;
      }
    }
  }
}

__global__ __launch_bounds__(256) void k_reduce(
    const float* __restrict__ eout, float* __restrict__ out) {
  const int i = blockIdx.x * 256 + threadIdx.x;
  if (i < BATCH * OUTD) {
    float s = 0.f;
    #pragma unroll
    for (int e = 0; e < NE; e++) s += eout[(size_t)e * (BATCH * OUTD) + i];
    out[i] = s;
  }
}

extern "C" void kernel_launch(void* const* d_in, const int* in_sizes, int n_in,
                              void* d_out, int out_size, void* d_ws, size_t ws_size,
                              hipStream_t stream) {
  (void)in_sizes; (void)n_in; (void)out_size; (void)ws_size;
  const float* proprio   = (const float*)d_in[0];
  const float* camera    = (const float*)d_in[1];
  const float* enc_w1    = (const float*)d_in[2];
  const float* enc_b1    = (const float*)d_in[3];
  const float* enc_w2    = (const float*)d_in[4];
  const float* enc_b2    = (const float*)d_in[5];
  const float* enc_ln_g  = (const float*)d_in[6];
  const float* enc_ln_b  = (const float*)d_in[7];
  const float* conv1_w   = (const float*)d_in[8];
  const float* conv1_b   = (const float*)d_in[9];
  const float* conv2_w   = (const float*)d_in[10];
  const float* conv2_b   = (const float*)d_in[11];
  const float* cnn_lin_w = (const float*)d_in[12];
  const float* cnn_lin_b = (const float*)d_in[13];
  const float* cnn_ln_g  = (const float*)d_in[14];
  const float* cnn_ln_b  = (const float*)d_in[15];
  const float* rw1 = (const float*)d_in[16];
  const float* rb1 = (const float*)d_in[17];
  const float* rw2 = (const float*)d_in[18];
  const float* rb2 = (const float*)d_in[19];
  const float* rw3 = (const float*)d_in[20];
  const float* rb3 = (const float*)d_in[21];
  const float* ew1 = (const float*)d_in[22];
  const float* eb1 = (const float*)d_in[23];
  const float* ew2 = (const float*)d_in[24];
  const float* eb2 = (const float*)d_in[25];
  const float* ew3 = (const float*)d_in[26];
  const float* eb3 = (const float*)d_in[27];
  const float* ew4 = (const float*)d_in[28];
  const float* eb4 = (const float*)d_in[29];
  float* out = (float*)d_out;

  // ws: lat16 (tiled+swizzled bf16) | gate f32 | eout f32 | wt1-3 | w4t | cnnWb | w2g | convflat
  unsigned short* lat16 = (unsigned short*)d_ws;
  float* gate = (float*)(lat16 + (size_t)BATCH * 256);
  float* eout = gate + (size_t)BATCH * NE;
  unsigned short* wt1 = (unsigned short*)(eout + (size_t)NE * BATCH * OUTD);
  unsigned short* wt2 = wt1 + (size_t)NE * 65536;
  unsigned short* wt3 = wt2 + (size_t)NE * 65536;
  unsigned short* w4t = wt3 + (size_t)NE * 65536;
  unsigned short* cnnWb = w4t + (size_t)NE * 4096;
  unsigned short* w2g = cnnWb + (size_t)192 * 2048;
  unsigned short* convflat = w2g + (size_t)32 * 256;

  k_wt<<<dim3(4, 4, 48), dim3(256), 0, stream>>>(ew1, ew2, ew3, wt1, wt2, wt3);
  k_w4t<<<dim3(16), dim3(256), 0, stream>>>(ew4, w4t);
  k_cnnw<<<dim3(32, 3), dim3(256), 0, stream>>>(cnn_lin_w, cnnWb);
  k_w2c<<<dim3(1), dim3(256), 0, stream>>>(conv2_w, w2g);
  k_proprio<<<dim3(512), dim3(256), 0, stream>>>(proprio, enc_w1, enc_b1, enc_w2, enc_b2,
                                                 enc_ln_g, enc_ln_b, lat16);
  for (int ch = 0; ch < 2; ch++) {
    k_conv<<<dim3(8192), dim3(256), 0, stream>>>(camera + (size_t)ch * 8192 * 1024,
                                                 conv1_w, conv1_b, w2g, conv2_b, convflat);
    k_cnnlin<<<dim3(256), dim3(256), 0, stream>>>(convflat, cnnWb, cnn_lin_b,
                                                  cnn_ln_g, cnn_ln_b, lat16, ch * 8192);
  }
  k_router<<<dim3(512), dim3(256), 0, stream>>>(lat16, rw1, rb1, rw2, rb2, rw3, rb3, gate);
  k_experts<<<dim3(16, 128), dim3(256), 0, stream>>>(lat16, gate, wt1, wt2, wt3, w4t,
                                                     eb1, eb2, eb3, eb4, eout);
  k_reduce<<<dim3(768), dim3(256), 0, stream>>>(eout, out);
}

// Round 5
// 608.339 us; speedup vs baseline: 4.1355x; 1.0473x over previous
//
#include <hip/hip_runtime.h>
#include <math.h>

#define BATCH 16384
#define LATD 256
#define OUTD 12
#define NE 16

typedef short bf16x8 __attribute__((ext_vector_type(8)));
typedef float f32x4 __attribute__((ext_vector_type(4)));
typedef unsigned short u16x8 __attribute__((ext_vector_type(8)));

__device__ __forceinline__ float elu_f(float x) { return x > 0.f ? x : expm1f(x); }
__device__ __forceinline__ float elu_fast(float x) { return x > 0.f ? x : (__expf(x) - 1.f); }

__device__ __forceinline__ unsigned short f2bf(float f) {
  union { float f; unsigned int u; } a; a.f = f;
  unsigned int u = a.u;
  unsigned int r = (u + 0x7FFFu + ((u >> 16) & 1u)) >> 16;
  return (unsigned short)r;
}
__device__ __forceinline__ float bf2f(unsigned short h) {
  union { unsigned int u; float f; } a; a.u = ((unsigned int)h) << 16;
  return a.f;
}

// XOR swizzle on byte address within a 512B-row tile (bank-conflict fix).
__device__ __forceinline__ int swz(int b) { return b ^ (((b >> 9) & 7) << 4); }

// lat16 layout: tiles of 128 rows; tile rb = row>>7; within tile, byte
// addr = swz((row&127)*512 + col*2). Tile stride 65536 B.

// ---------------- proprio encoder: 256 ->128 elu ->64 + LN -> lat16 cols 0..63 ----------------
__global__ __launch_bounds__(256) void k_proprio(
    const float* __restrict__ P,
    const float* __restrict__ W1, const float* __restrict__ B1,
    const float* __restrict__ W2, const float* __restrict__ B2,
    const float* __restrict__ G, const float* __restrict__ Bn,
    unsigned short* __restrict__ lat16) {
  __shared__ __align__(16) float a[32][256];
  __shared__ float h[32][128];
  __shared__ float d[32][64];
  __shared__ float mrow[32], irow[32];
  const int t = threadIdx.x;
  const size_t row0 = (size_t)blockIdx.x * 32;
  {
    const float4* s = (const float4*)(P + row0 * 256);
    float4* dd = (float4*)&a[0][0];
    #pragma unroll
    for (int i = 0; i < 8; i++) dd[t + i * 256] = s[t + i * 256];
  }
  __syncthreads();
  {
    const int c = t & 127, g0 = (t >> 7) * 16;
    float acc[16];
    #pragma unroll
    for (int i = 0; i < 16; i++) acc[i] = 0.f;
    for (int k = 0; k < 256; k++) {
      const float w = W1[k * 128 + c];
      #pragma unroll
      for (int i = 0; i < 16; i++) acc[i] += a[g0 + i][k] * w;
    }
    const float bb = B1[c];
    #pragma unroll
    for (int i = 0; i < 16; i++) h[g0 + i][c] = elu_f(acc[i] + bb);
  }
  __syncthreads();
  {
    const int c = t & 63, g0 = (t >> 6) * 8;
    float acc[8];
    #pragma unroll
    for (int i = 0; i < 8; i++) acc[i] = 0.f;
    for (int k = 0; k < 128; k++) {
      const float w = W2[k * 64 + c];
      #pragma unroll
      for (int i = 0; i < 8; i++) acc[i] += h[g0 + i][k] * w;
    }
    const float bb = B2[c];
    #pragma unroll
    for (int i = 0; i < 8; i++) d[g0 + i][c] = acc[i] + bb;
  }
  __syncthreads();
  if (t < 32) {
    float m = 0.f;
    for (int j = 0; j < 64; j++) m += d[t][j];
    m *= (1.f / 64.f);
    float v = 0.f;
    for (int j = 0; j < 64; j++) { float x = d[t][j] - m; v += x * x; }
    v *= (1.f / 64.f);
    mrow[t] = m; irow[t] = 1.f / sqrtf(v + 1e-5f);
  }
  __syncthreads();
  {  // 32 rows x 8 chunks of 8 cols -> swizzled bf16 store
    const int r = t >> 3, ch = t & 7;
    const size_t grow = row0 + r;
    const size_t rb = grow >> 7;
    const int loc = (int)(grow & 127);
    u16x8 o;
    #pragma unroll
    for (int q = 0; q < 8; q++) {
      const int c = ch * 8 + q;
      o[q] = f2bf((d[r][c] - mrow[r]) * irow[r] * G[c] + Bn[c]);
    }
    *(u16x8*)((char*)lat16 + rb * 65536 + swz(loc * 512 + ch * 16)) = o;
  }
}

// ---------------- conv2 weight prep: C2W [co][ci][3][3] f32 -> w2g bf16 [co][ci*16+tap] ----------------
__global__ __launch_bounds__(256) void k_w2c(
    const float* __restrict__ C2W, unsigned short* __restrict__ w2g) {
  const int t = threadIdx.x;
  const int co = t >> 3, ci0 = t & 7;
  #pragma unroll
  for (int hh = 0; hh < 2; hh++) {
    const int ci = ci0 + hh * 8;
    #pragma unroll
    for (int tap = 0; tap < 16; tap++) {
      w2g[co * 256 + ci * 16 + tap] =
          (tap < 9) ? f2bf(C2W[co * 144 + ci * 9 + tap]) : (unsigned short)0;
    }
  }
}

// ---------------- conv1 (VALU) + conv2 (implicit-GEMM MFMA), flatten -> bf16 ----------------
__global__ __launch_bounds__(256) void k_conv(
    const float* __restrict__ cam,
    const float* __restrict__ C1W, const float* __restrict__ C1B,
    const unsigned short* __restrict__ w2g, const float* __restrict__ C2B,
    unsigned short* __restrict__ flat) {
  __shared__ __align__(16) float img[32 * 36];          // pitch 36, cols 32-35 zero
  __shared__ float w1s[144];
  __shared__ __align__(16) unsigned short c1[16 * 17 * 20];  // [ci][17 rows][20 cols] bf16
  __shared__ __align__(16) unsigned short Bm[64 * 256];      // im2col B, swizzled, 32KB
  __shared__ __align__(16) unsigned short obuf[2048];
  const int t = threadIdx.x;
  const int lane = t & 63, w = t >> 6;
  const int lr = lane & 15, lg = lane >> 4;
  const size_t b = blockIdx.x;
  char* c1b = (char*)c1;
  char* bmb = (char*)Bm;
  {
    const float* ip = cam + b * 1024;
    for (int i = t; i < 1024; i += 256) img[(i >> 5) * 36 + (i & 31)] = ip[i];
    if (t < 32) *(float4*)&img[t * 36 + 32] = make_float4(0.f, 0.f, 0.f, 0.f);
    if (t < 144) w1s[t] = C1W[t];
    if (t < 80) *(ushort4*)(c1b + (t / 5) * 680 + 640 + (t % 5) * 8) = make_ushort4(0, 0, 0, 0);
  }
  __syncthreads();
  {  // conv1
    const int c = t >> 4, y = t & 15;
    float acc[16];
    #pragma unroll
    for (int x = 0; x < 16; x++) acc[x] = 0.f;
    #pragma unroll
    for (int dy = 0; dy < 3; dy++) {
      const int row = 2 * y + dy;
      if (row < 32) {
        float4 f4[9];
        #pragma unroll
        for (int i = 0; i < 9; i++) f4[i] = *(const float4*)&img[row * 36 + 4 * i];
        const float* rr = (const float*)f4;
        const float wa = w1s[c * 9 + dy * 3], wb = w1s[c * 9 + dy * 3 + 1], wc = w1s[c * 9 + dy * 3 + 2];
        #pragma unroll
        for (int x = 0; x < 16; x++) acc[x] += wa * rr[2 * x] + wb * rr[2 * x + 1] + wc * rr[2 * x + 2];
      }
    }
    const float bb = C1B[c];
    #pragma unroll
    for (int p = 0; p < 4; p++) {
      ushort4 v;
      v.x = f2bf(elu_fast(acc[4 * p + 0] + bb));
      v.y = f2bf(elu_fast(acc[4 * p + 1] + bb));
      v.z = f2bf(elu_fast(acc[4 * p + 2] + bb));
      v.w = f2bf(elu_fast(acc[4 * p + 3] + bb));
      *(ushort4*)(c1b + c * 680 + y * 40 + p * 8) = v;
    }
    *(ushort4*)(c1b + c * 680 + y * 40 + 32) = make_ushort4(0, 0, 0, 0);
  }
  __syncthreads();
  {  // im2col
    #pragma unroll
    for (int i = 0; i < 4; i++) {
      const int item = i * 256 + t;
      const int m = item & 63, ci = item >> 6;
      const int y = m >> 3, x = m & 7;
      unsigned int pr[3]; unsigned short th[3];
      #pragma unroll
      for (int dy = 0; dy < 3; dy++) {
        const int base = ci * 680 + (2 * y + dy) * 40 + 4 * x;
        pr[dy] = *(const unsigned int*)(c1b + base);
        th[dy] = *(const unsigned short*)(c1b + base + 4);
      }
      uint4 u0;
      u0.x = pr[0];
      u0.y = ((unsigned int)th[0]) | (((unsigned int)(pr[1] & 0xFFFFu)) << 16);
      u0.z = (pr[1] >> 16) | (((unsigned int)th[1]) << 16);
      u0.w = pr[2];
      uint4 u1;
      u1.x = (unsigned int)th[2];
      u1.y = 0; u1.z = 0; u1.w = 0;
      const int bb0 = m * 512 + ci * 32;
      *(uint4*)(bmb + swz(bb0)) = u0;
      *(uint4*)(bmb + swz(bb0 + 16)) = u1;
    }
  }
  __syncthreads();
  {  // GEMM: out[co 32][m 64] = w2g . B^T
    f32x4 acc[2];
    acc[0] = (f32x4){0.f, 0.f, 0.f, 0.f};
    acc[1] = (f32x4){0.f, 0.f, 0.f, 0.f};
    const int mbase = (w * 16 + lr) * 512 + lg * 16;
    #pragma unroll
    for (int ks = 0; ks < 8; ks++) {
      const bf16x8 bfr = *(const bf16x8*)(bmb + swz(mbase + ks * 64));
      #pragma unroll
      for (int nt = 0; nt < 2; nt++) {
        const bf16x8 af = *(const bf16x8*)(w2g + (nt * 16 + lr) * 256 + ks * 32 + lg * 8);
        acc[nt] = __builtin_amdgcn_mfma_f32_16x16x32_bf16(af, bfr, acc[nt], 0, 0, 0);
      }
    }
    #pragma unroll
    for (int nt = 0; nt < 2; nt++) {
      const float4 bb = *(const float4*)(C2B + nt * 16 + 4 * lg);
      const float bv[4] = { bb.x, bb.y, bb.z, bb.w };
      #pragma unroll
      for (int q = 0; q < 4; q++) {
        const int co = nt * 16 + 4 * lg + q;
        obuf[co * 64 + w * 16 + lr] = f2bf(elu_fast(acc[nt][q] + bv[q]));
      }
    }
  }
  __syncthreads();
  *(u16x8*)(flat + b * 2048 + t * 8) = *(const u16x8*)(obuf + t * 8);
}

// ---------------- cnn_lin_w [2048][192] f32 -> Wb [192][2048] bf16 ----------------
__global__ __launch_bounds__(256) void k_cnnw(
    const float* __restrict__ W, unsigned short* __restrict__ Wb) {
  __shared__ float tile[64][65];
  const int t = threadIdx.x;
  const int k0 = blockIdx.x * 64, j0 = blockIdx.y * 64;
  for (int idx = t; idx < 4096; idx += 256) {
    const int kk = idx >> 6, jj = idx & 63;
    tile[kk][jj] = W[(size_t)(k0 + kk) * 192 + j0 + jj];
  }
  __syncthreads();
  for (int idx = t; idx < 4096; idx += 256) {
    const int jj = idx >> 6, kk = idx & 63;
    Wb[(size_t)(j0 + jj) * 2048 + k0 + kk] = f2bf(tile[kk][jj]);
  }
}

// ---------------- cnn linear via MFMA: BM=32, +bias, LN -> lat16 cols 64..255 ----------------
__global__ __launch_bounds__(256) void k_cnnlin(
    const unsigned short* __restrict__ Xc, const unsigned short* __restrict__ Wb,
    const float* __restrict__ bias, const float* __restrict__ G,
    const float* __restrict__ Bn, unsigned short* __restrict__ lat16, int row_base) {
  __shared__ __align__(16) unsigned short XS[32 * 256];
  __shared__ __align__(16) float Yl[32 * 196];
  __shared__ float mrow[32], irow[32];
  char* xsb = (char*)XS;
  const int t = threadIdx.x;
  const int lane = t & 63, w = t >> 6;
  const int lr = lane & 15, lg = lane >> 4;
  const int b0 = blockIdx.x * 32;
  const int j0w = w * 48;

  f32x4 acc[3][2];
  #pragma unroll
  for (int jt = 0; jt < 3; jt++)
    #pragma unroll
    for (int mt = 0; mt < 2; mt++) acc[jt][mt] = (f32x4){0.f, 0.f, 0.f, 0.f};

  for (int kc = 0; kc < 8; kc++) {
    #pragma unroll
    for (int i = 0; i < 4; i++) {
      const int f = t + i * 256;
      const int m = f >> 5;
      const int kof = (f & 31) * 8;
      const u16x8 v = *(const u16x8*)(Xc + (size_t)(b0 + m) * 2048 + kc * 256 + kof);
      *(u16x8*)(xsb + swz(m * 512 + kof * 2)) = v;
    }
    __syncthreads();
    #pragma unroll
    for (int ks = 0; ks < 8; ks++) {
      bf16x8 af[3], bfr[2];
      #pragma unroll
      for (int jt = 0; jt < 3; jt++)
        af[jt] = *(const bf16x8*)(Wb + (size_t)(j0w + jt * 16 + lr) * 2048 + kc * 256 + ks * 32 + lg * 8);
      #pragma unroll
      for (int mt = 0; mt < 2; mt++)
        bfr[mt] = *(const bf16x8*)(xsb + swz((mt * 16 + lr) * 512 + lg * 16 + ks * 64));
      #pragma unroll
      for (int jt = 0; jt < 3; jt++)
        #pragma unroll
        for (int mt = 0; mt < 2; mt++)
          acc[jt][mt] = __builtin_amdgcn_mfma_f32_16x16x32_bf16(af[jt], bfr[mt], acc[jt][mt], 0, 0, 0);
    }
    __syncthreads();
  }
  #pragma unroll
  for (int jt = 0; jt < 3; jt++) {
    const int j0 = j0w + jt * 16 + 4 * lg;
    const float4 bb = *(const float4*)(bias + j0);
    #pragma unroll
    for (int mt = 0; mt < 2; mt++) {
      const int m = mt * 16 + lr;
      f32x4 v = acc[jt][mt];
      v[0] += bb.x; v[1] += bb.y; v[2] += bb.z; v[3] += bb.w;
      *(f32x4*)&Yl[m * 196 + j0] = v;
    }
  }
  __syncthreads();
  if (t < 32) {
    float m = 0.f;
    for (int q = 0; q < 48; q++) {
      const f32x4 v = *(const f32x4*)&Yl[t * 196 + q * 4];
      m += v[0] + v[1] + v[2] + v[3];
    }
    m *= (1.f / 192.f);
    float var = 0.f;
    for (int q = 0; q < 48; q++) {
      const f32x4 v = *(const f32x4*)&Yl[t * 196 + q * 4];
      #pragma unroll
      for (int z = 0; z < 4; z++) { const float x = v[z] - m; var += x * x; }
    }
    var *= (1.f / 192.f);
    mrow[t] = m; irow[t] = 1.f / sqrtf(var + 1e-5f);
  }
  __syncthreads();
  {
    #pragma unroll
    for (int i = 0; i < 3; i++) {
      const int item = t + i * 256;
      const int m = item / 24, cq = item % 24;
      const float mm = mrow[m], iv = irow[m];
      u16x8 o;
      #pragma unroll
      for (int q = 0; q < 8; q++) {
        const int j = cq * 8 + q;
        o[q] = f2bf((Yl[m * 196 + j] - mm) * iv * G[j] + Bn[j]);
      }
      const size_t grow = (size_t)(row_base + b0 + m);
      const size_t rb = grow >> 7;
      const int loc = (int)(grow & 127);
      *(u16x8*)((char*)lat16 + rb * 65536 + swz(loc * 512 + 128 + cq * 16)) = o;
    }
  }
}

// ---------------- router: reads bf16 lat16 ----------------
__global__ __launch_bounds__(256) void k_router(
    const unsigned short* __restrict__ lat16,
    const float* __restrict__ W1, const float* __restrict__ B1,
    const float* __restrict__ W2, const float* __restrict__ B2,
    const float* __restrict__ W3, const float* __restrict__ B3,
    float* __restrict__ gate) {
  __shared__ __align__(16) float a[32][256];
  __shared__ float h1[32][128];
  __shared__ float h2[32][64];
  __shared__ float lg[32][16];
  const int t = threadIdx.x;
  const size_t row0 = (size_t)blockIdx.x * 32;
  {
    #pragma unroll
    for (int i = 0; i < 4; i++) {
      const int cc = t + i * 256;
      const int r = cc >> 5, kc = cc & 31;
      const size_t grow = row0 + r;
      const size_t rb = grow >> 7;
      const int loc = (int)(grow & 127);
      const u16x8 h = *(const u16x8*)((const char*)lat16 + rb * 65536 + swz(loc * 512 + kc * 16));
      #pragma unroll
      for (int q = 0; q < 8; q++) a[r][kc * 8 + q] = bf2f(h[q]);
    }
  }
  __syncthreads();
  {
    const int c = t & 127, g0 = (t >> 7) * 16;
    float acc[16];
    #pragma unroll
    for (int i = 0; i < 16; i++) acc[i] = 0.f;
    for (int k = 0; k < 256; k++) {
      const float w = W1[k * 128 + c];
      #pragma unroll
      for (int i = 0; i < 16; i++) acc[i] += a[g0 + i][k] * w;
    }
    const float bb = B1[c];
    #pragma unroll
    for (int i = 0; i < 16; i++) h1[g0 + i][c] = elu_f(acc[i] + bb);
  }
  __syncthreads();
  {
    const int c = t & 63, g0 = (t >> 6) * 8;
    float acc[8];
    #pragma unroll
    for (int i = 0; i < 8; i++) acc[i] = 0.f;
    for (int k = 0; k < 128; k++) {
      const float w = W2[k * 64 + c];
      #pragma unroll
      for (int i = 0; i < 8; i++) acc[i] += h1[g0 + i][k] * w;
    }
    const float bb = B2[c];
    #pragma unroll
    for (int i = 0; i < 8; i++) h2[g0 + i][c] = elu_f(acc[i] + bb);
  }
  __syncthreads();
  for (int o = t; o < 512; o += 256) {
    const int r = o >> 4, c = o & 15;
    float acc = 0.f;
    for (int k = 0; k < 64; k++) acc += h2[r][k] * W3[k * 16 + c];
    lg[r][c] = acc + B3[c];
  }
  __syncthreads();
  if (t < 32) {
    float m = lg[t][0];
    for (int c = 1; c < 16; c++) m = fmaxf(m, lg[t][c]);
    float s = 0.f;
    float ex[16];
    for (int c = 0; c < 16; c++) { ex[c] = expf(lg[t][c] - m); s += ex[c]; }
    const float inv = 1.f / s;
    for (int c = 0; c < 16; c++) gate[(row0 + t) * 16 + c] = ex[c] * inv;
  }
}

// ---------------- expert weight transpose+convert ----------------
__global__ __launch_bounds__(256) void k_wt(
    const float* __restrict__ ew1, const float* __restrict__ ew2, const float* __restrict__ ew3,
    unsigned short* __restrict__ wt1, unsigned short* __restrict__ wt2, unsigned short* __restrict__ wt3) {
  __shared__ float tile[64][65];
  const int t = threadIdx.x;
  const int zl = blockIdx.z;
  const int layer = zl >> 4, e = zl & 15;
  const float* src = (layer == 0 ? ew1 : layer == 1 ? ew2 : ew3) + (size_t)e * 65536;
  unsigned short* dst = (layer == 0 ? wt1 : layer == 1 ? wt2 : wt3) + (size_t)e * 65536;
  const int k0 = blockIdx.x * 64, j0 = blockIdx.y * 64;
  for (int idx = t; idx < 4096; idx += 256) {
    const int kk = idx >> 6, jj = idx & 63;
    tile[kk][jj] = src[(size_t)(k0 + kk) * 256 + j0 + jj];
  }
  __syncthreads();
  for (int idx = t; idx < 4096; idx += 256) {
    const int jj = idx >> 6, kk = idx & 63;
    dst[(size_t)(j0 + jj) * 256 + k0 + kk] = f2bf(tile[kk][jj]);
  }
}

__global__ __launch_bounds__(256) void k_w4t(
    const float* __restrict__ ew4, unsigned short* __restrict__ w4t) {
  const int e = blockIdx.x, k = threadIdx.x;
  #pragma unroll
  for (int j = 0; j < 16; j++) {
    const float v = (j < 12) ? ew4[(size_t)e * 3072 + k * 12 + j] : 0.f;
    w4t[(size_t)e * 4096 + j * 256 + k] = f2bf(v);
  }
}

// ---------------- experts: BM=64, ping-pong LDS, XCD-chunked grid, 4 barriers ----------------
// grid 4096 flat: xcd=bid&7 owns rb range [xcd*32, +32); within XCD e-slow, rb-fast
// -> per-XCD L2 holds its 1MB latent range + current expert's weights.
__global__ __launch_bounds__(256, 2) void k_experts(
    const unsigned short* __restrict__ lat16, const float* __restrict__ gate,
    const unsigned short* __restrict__ wt1, const unsigned short* __restrict__ wt2,
    const unsigned short* __restrict__ wt3, const unsigned short* __restrict__ w4t,
    const float* __restrict__ EB1, const float* __restrict__ EB2,
    const float* __restrict__ EB3, const float* __restrict__ EB4,
    float* __restrict__ eout) {
  __shared__ __align__(16) unsigned short Xa[64 * 256];  // 32KB
  __shared__ __align__(16) unsigned short Xb[64 * 256];  // 32KB
  char* sa = (char*)Xa;
  char* sb = (char*)Xb;
  const int t = threadIdx.x;
  const int lane = t & 63, w = t >> 6;
  const int lr = lane & 15, lg = lane >> 4;
  const int bid = blockIdx.x;
  const int xcd = bid & 7, l = bid >> 3;
  const int e = l >> 5;                  // e slow within XCD
  const int rb = xcd * 32 + (l & 31);    // rb fast within XCD
  const int row0 = rb * 64;

  // hoist gate value (one row per lane for layer-4 epilogue)
  const float gv = gate[(size_t)(row0 + w * 16 + lr) * 16 + e];

  {  // stage 32KB half-tile (source already swizzled; swz row-period 8 | 64)
    const uint4* s = (const uint4*)(lat16 + (size_t)(rb >> 1) * 32768 + (size_t)(rb & 1) * 16384);
    uint4* dd = (uint4*)Xa;
    #pragma unroll
    for (int i = 0; i < 8; i++) dd[t + i * 256] = s[t + i * 256];
  }
  __syncthreads();

  const unsigned short* Wl[3] = {
    wt1 + (size_t)e * 65536, wt2 + (size_t)e * 65536, wt3 + (size_t)e * 65536 };
  const float* Bl[3] = { EB1 + e * 256, EB2 + e * 256, EB3 + e * 256 };
  const int wjb = w * 64;

  int mtb[4];
  #pragma unroll
  for (int mt = 0; mt < 4; mt++) mtb[mt] = (mt * 16 + lr) * 512 + lg * 16;

  #pragma unroll
  for (int lyr = 0; lyr < 3; lyr++) {
    const unsigned short* W = Wl[lyr];
    const char* src = (lyr & 1) ? sb : sa;   // L0:Xa->Xb, L1:Xb->Xa, L2:Xa->Xb
    char* dst = (lyr & 1) ? sa : sb;
    f32x4 acc[4][4];
    #pragma unroll
    for (int jt = 0; jt < 4; jt++)
      #pragma unroll
      for (int mt = 0; mt < 4; mt++) acc[jt][mt] = (f32x4){0.f, 0.f, 0.f, 0.f};
    const size_t wlane = (size_t)(wjb + lr) * 256 + lg * 8;
    for (int ks = 0; ks < 8; ks++) {
      bf16x8 af[4], bfr[4];
      #pragma unroll
      for (int jt = 0; jt < 4; jt++)
        af[jt] = *(const bf16x8*)(W + wlane + jt * 4096 + ks * 32);
      #pragma unroll
      for (int mt = 0; mt < 4; mt++)
        bfr[mt] = *(const bf16x8*)(src + swz(mtb[mt] + ks * 64));
      __builtin_amdgcn_s_setprio(1);
      #pragma unroll
      for (int jt = 0; jt < 4; jt++)
        #pragma unroll
        for (int mt = 0; mt < 4; mt++)
          acc[jt][mt] = __builtin_amdgcn_mfma_f32_16x16x32_bf16(af[jt], bfr[mt], acc[jt][mt], 0, 0, 0);
      __builtin_amdgcn_s_setprio(0);
    }
    // write to the OTHER buffer: no read/write barrier needed (disjoint per wave)
    const float* B = Bl[lyr];
    #pragma unroll
    for (int jt = 0; jt < 4; jt++) {
      const int j0 = wjb + jt * 16 + 4 * lg;
      const float4 bb = *(const float4*)(B + j0);
      #pragma unroll
      for (int mt = 0; mt < 4; mt++) {
        const int m = mt * 16 + lr;
        ushort4 h;
        h.x = f2bf(elu_fast(acc[jt][mt][0] + bb.x));
        h.y = f2bf(elu_fast(acc[jt][mt][1] + bb.y));
        h.z = f2bf(elu_fast(acc[jt][mt][2] + bb.z));
        h.w = f2bf(elu_fast(acc[jt][mt][3] + bb.w));
        *(ushort4*)(dst + swz(m * 512 + j0 * 2)) = h;
      }
    }
    __syncthreads();  // single barrier per layer
  }

  {  // layer 4: result lives in Xb; wave w owns m-tile w
    const unsigned short* W4 = w4t + (size_t)e * 4096;
    f32x4 a4 = (f32x4){0.f, 0.f, 0.f, 0.f};
    const size_t wl4 = (size_t)lr * 256 + lg * 8;
    const int mb = (w * 16 + lr) * 512 + lg * 16;
    #pragma unroll
    for (int ks = 0; ks < 8; ks++) {
      const bf16x8 a = *(const bf16x8*)(W4 + wl4 + ks * 32);
      const bf16x8 bv = *(const bf16x8*)(sb + swz(mb + ks * 64));
      a4 = __builtin_amdgcn_mfma_f32_16x16x32_bf16(a, bv, a4, 0, 0, 0);
    }
    const int row = row0 + w * 16 + lr;
    if (lg < 3) {
      const float4 bb = *(const float4*)(EB4 + e * 12 + 4 * lg);
      float4 o;
      o.x = gv * (a4[0] + bb.x);
      o.y = gv * (a4[1] + bb.y);
      o.z = gv * (a4[2] + bb.z);
      o.w = gv * (a4[3] + bb.w);
      *(float4*)(eout + ((size_t)e * BATCH + row) * 12 + 4 * lg) = o;
    }
  }
}

__global__ __launch_bounds__(256) void k_reduce(
    const float* __restrict__ eout, float* __restrict__ out) {
  const int i = blockIdx.x * 256 + threadIdx.x;
  if (i < BATCH * OUTD) {
    float s = 0.f;
    #pragma unroll
    for (int e = 0; e < NE; e++) s += eout[(size_t)e * (BATCH * OUTD) + i];
    out[i] = s;
  }
}

extern "C" void kernel_launch(void* const* d_in, const int* in_sizes, int n_in,
                              void* d_out, int out_size, void* d_ws, size_t ws_size,
                              hipStream_t stream) {
  (void)in_sizes; (void)n_in; (void)out_size; (void)ws_size;
  const float* proprio   = (const float*)d_in[0];
  const float* camera    = (const float*)d_in[1];
  const float* enc_w1    = (const float*)d_in[2];
  const float* enc_b1    = (const float*)d_in[3];
  const float* enc_w2    = (const float*)d_in[4];
  const float* enc_b2    = (const float*)d_in[5];
  const float* enc_ln_g  = (const float*)d_in[6];
  const float* enc_ln_b  = (const float*)d_in[7];
  const float* conv1_w   = (const float*)d_in[8];
  const float* conv1_b   = (const float*)d_in[9];
  const float* conv2_w   = (const float*)d_in[10];
  const float* conv2_b   = (const float*)d_in[11];
  const float* cnn_lin_w = (const float*)d_in[12];
  const float* cnn_lin_b = (const float*)d_in[13];
  const float* cnn_ln_g  = (const float*)d_in[14];
  const float* cnn_ln_b  = (const float*)d_in[15];
  const float* rw1 = (const float*)d_in[16];
  const float* rb1 = (const float*)d_in[17];
  const float* rw2 = (const float*)d_in[18];
  const float* rb2 = (const float*)d_in[19];
  const float* rw3 = (const float*)d_in[20];
  const float* rb3 = (const float*)d_in[21];
  const float* ew1 = (const float*)d_in[22];
  const float* eb1 = (const float*)d_in[23];
  const float* ew2 = (const float*)d_in[24];
  const float* eb2 = (const float*)d_in[25];
  const float* ew3 = (const float*)d_in[26];
  const float* eb3 = (const float*)d_in[27];
  const float* ew4 = (const float*)d_in[28];
  const float* eb4 = (const float*)d_in[29];
  float* out = (float*)d_out;

  unsigned short* lat16 = (unsigned short*)d_ws;
  float* gate = (float*)(lat16 + (size_t)BATCH * 256);
  float* eout = gate + (size_t)BATCH * NE;
  unsigned short* wt1 = (unsigned short*)(eout + (size_t)NE * BATCH * OUTD);
  unsigned short* wt2 = wt1 + (size_t)NE * 65536;
  unsigned short* wt3 = wt2 + (size_t)NE * 65536;
  unsigned short* w4t = wt3 + (size_t)NE * 65536;
  unsigned short* cnnWb = w4t + (size_t)NE * 4096;
  unsigned short* w2g = cnnWb + (size_t)192 * 2048;
  unsigned short* convflat = w2g + (size_t)32 * 256;

  k_wt<<<dim3(4, 4, 48), dim3(256), 0, stream>>>(ew1, ew2, ew3, wt1, wt2, wt3);
  k_w4t<<<dim3(16), dim3(256), 0, stream>>>(ew4, w4t);
  k_cnnw<<<dim3(32, 3), dim3(256), 0, stream>>>(cnn_lin_w, cnnWb);
  k_w2c<<<dim3(1), dim3(256), 0, stream>>>(conv2_w, w2g);
  k_proprio<<<dim3(512), dim3(256), 0, stream>>>(proprio, enc_w1, enc_b1, enc_w2, enc_b2,
                                                 enc_ln_g, enc_ln_b, lat16);
  for (int ch = 0; ch < 2; ch++) {
    k_conv<<<dim3(8192), dim3(256), 0, stream>>>(camera + (size_t)ch * 8192 * 1024,
                                                 conv1_w, conv1_b, w2g, conv2_b, convflat);
    k_cnnlin<<<dim3(256), dim3(256), 0, stream>>>(convflat, cnnWb, cnn_lin_b,
                                                  cnn_ln_g, cnn_ln_b, lat16, ch * 8192);
  }
  k_router<<<dim3(512), dim3(256), 0, stream>>>(lat16, rw1, rb1, rw2, rb2, rw3, rb3, gate);
  k_experts<<<dim3(4096), dim3(256), 0, stream>>>(lat16, gate, wt1, wt2, wt3, w4t,
                                                  eb1, eb2, eb3, eb4, eout);
  k_reduce<<<dim3(768), dim3(256), 0, stream>>>(eout, out);
}